// Round 16
// baseline (145.859 us; speedup 1.0000x reference)
//
#include <hip/hip_runtime.h>
#include <hip/hip_bf16.h>
#include <stdint.h>
#include <stddef.h>

#define S_LEN 4096
#define EMB   1280
#define NH    16
#define HDIM  80
#define N3    3840
#define QSCALE 0.11180339887498949f   // 1/sqrt(80)
#define LOG2E  1.4426950408889634f

typedef __attribute__((ext_vector_type(4))) float f32x4;
typedef __attribute__((ext_vector_type(16))) float f32x16;
typedef __attribute__((ext_vector_type(4))) short s16x4;
typedef __attribute__((ext_vector_type(8))) short s16x8;
typedef __attribute__((ext_vector_type(8))) __bf16 bf16x8;

typedef __attribute__((address_space(1))) const unsigned int as1_u32;
typedef __attribute__((address_space(3))) unsigned int as3_u32;

__device__ __forceinline__ unsigned short f2bf(float f) {
  return __builtin_bit_cast(unsigned short, __float2bfloat16(f));
}
__device__ __forceinline__ float bf2f(unsigned short b) {
  union { unsigned int u; float f; } v; v.u = ((unsigned int)b) << 16;
  return v.f;
}

__device__ __forceinline__ f32x4 mfma16(s16x8 a, s16x8 b, f32x4 c) {
  return __builtin_amdgcn_mfma_f32_16x16x32_bf16(
      __builtin_bit_cast(bf16x8, a), __builtin_bit_cast(bf16x8, b), c, 0, 0, 0);
}
__device__ __forceinline__ f32x16 mfma32(s16x8 a, s16x8 b, f32x16 c) {
  return __builtin_amdgcn_mfma_f32_32x32x16_bf16(
      __builtin_bit_cast(bf16x8, a), __builtin_bit_cast(bf16x8, b), c, 0, 0, 0);
}

__device__ __forceinline__ unsigned cvtpk_bf16(float a, float b) {
  unsigned r;
  asm("v_cvt_pk_bf16_f32 %0, %1, %2" : "=v"(r) : "v"(a), "v"(b));
  return r;
}

// raw hardware exp2
__device__ __forceinline__ float fexp2(float x) {
  float r;
  asm("v_exp_f32 %0, %1" : "=v"(r) : "v"(x));
  return r;
}

__device__ __forceinline__ void gload16(const void* g, void* l) {
  __builtin_amdgcn_global_load_lds((as1_u32*)g, (as3_u32*)l, 16, 0, 0);
}

// ---------------- convert f32 -> bf16 (vectorized) ----------------
__global__ __launch_bounds__(256) void cvt_kernel(const float* __restrict__ in,
                                                  unsigned short* __restrict__ out, int n4) {
  int i = blockIdx.x * 256 + threadIdx.x;
  if (i >= n4) return;
  float4 v = ((const float4*)in)[i];
  s16x4 o;
  o[0] = (short)f2bf(v.x); o[1] = (short)f2bf(v.y);
  o[2] = (short)f2bf(v.z); o[3] = (short)f2bf(v.w);
  ((s16x4*)out)[i] = o;
}

// ---------------- cos/sin tables ----------------
__global__ __launch_bounds__(256) void rope_tab_kernel(const float* __restrict__ rope,
                                                       float* __restrict__ cosT,
                                                       float* __restrict__ sinT, int n) {
  int i = blockIdx.x * 256 + threadIdx.x;
  if (i >= n) return;
  float v = rope[i];
  float s, c;
  sincosf(v, &s, &c);
  cosT[i] = c; sinT[i] = s;
}

// ------- 256x256 bf16 GEMM, 4-slot K-32 ring pipeline, C = A*B^T + bias -------
// 512 threads = 8 waves (2M x 4N). LDS: 4 slots x (256 x 32) per operand = 128KB.
// Per K-32 step (slot s = k&3):
//   vmcnt(12|8|4|0 tail-exact)  <- stage(k) landed (12 = 3 younger stages x 4)
//   barrier                     <- ALL waves' stage(k) landed
//   12 ds_read_b128 (slot s) ; setprio(1) 32 MFMA setprio(0)
//   lgkmcnt(0); barrier         <- all waves done reading slot s
//   STAGE(slot s <- k+4)        <- 4-step prefetch slack (~4000cy)
// Pair-swizzle (64B rows share 128B line): phys8 = (side*4+g) ^ (pair&7);
// fragment reads hit each bank-group exactly 2x (free); LDS dest lane-linear.
template<int BF16OUT>
__global__ __launch_bounds__(512, 2) void gemm256_kernel(const unsigned short* __restrict__ A,
                                                         const unsigned short* __restrict__ B,
                                                         const float* __restrict__ bias,
                                                         void* __restrict__ Cv,
                                                         int M, int N, int K,
                                                         int gx, int gy) {
  __shared__ __attribute__((aligned(16))) unsigned short lA[4][8192];
  __shared__ __attribute__((aligned(16))) unsigned short lB[4][8192];
  const int t = threadIdx.x;
  const int lane = t & 63, g = lane >> 4, c = lane & 15;
  const int w = t >> 6, wm = w >> 2, wn = w & 3;

  int nwg = gx * gy;
  int bid = blockIdx.x;
  int cpx = nwg >> 3;
  int swz = (bid & 7) * cpx + (bid >> 3);
  const int m0 = (swz / gx) * 256, n0 = (swz % gx) * 256;
  const int nt = K >> 5;   // K-32 steps

  // staging sources: linear dest chunk L -> (row, colc) via inverse pair-swizzle
  const unsigned short* aSrc[2];
  const unsigned short* bSrc[2];
#pragma unroll
  for (int i = 0; i < 2; ++i) {
    int L = t + i * 512;
    int phys8 = L & 7, p = L >> 3;
    int chunk3 = phys8 ^ (p & 7);
    int side = chunk3 >> 2, colc = chunk3 & 3;
    int row = p * 2 + side;
    aSrc[i] = A + (size_t)(m0 + row) * K + colc * 8;
    bSrc[i] = B + (size_t)(n0 + row) * K + colc * 8;
  }

#define STAGE(s, kt)                                        \
  do {                                                      \
    int _ko = (kt) * 32;                                    \
    gload16(aSrc[0] + _ko, &lA[s][t * 8]);                  \
    gload16(aSrc[1] + _ko, &lA[s][(t + 512) * 8]);          \
    gload16(bSrc[0] + _ko, &lB[s][t * 8]);                  \
    gload16(bSrc[1] + _ko, &lB[s][(t + 512) * 8]);          \
  } while (0)

  // ds_read offsets (hoisted): row -> pair/side -> swizzled ushort offset
  int offA[8], offB[4];
#pragma unroll
  for (int mf = 0; mf < 8; ++mf) {
    int row = wm * 128 + mf * 16 + c;
    int p = row >> 1, side = row & 1;
    offA[mf] = p * 64 + (((side * 4 + g) ^ (p & 7)) * 8);
  }
#pragma unroll
  for (int nf = 0; nf < 4; ++nf) {
    int row = wn * 64 + nf * 16 + c;
    int p = row >> 1, side = row & 1;
    offB[nf] = p * 64 + (((side * 4 + g) ^ (p & 7)) * 8);
  }

  const f32x4 fz = {0.f, 0.f, 0.f, 0.f};
  f32x4 acc[8][4];
#pragma unroll
  for (int i = 0; i < 8; ++i)
#pragma unroll
    for (int j = 0; j < 4; ++j) acc[i][j] = fz;

  STAGE(0, 0);
  STAGE(1, 1);
  STAGE(2, 2);
  STAGE(3, 3);

  for (int k = 0; k < nt; ++k) {
    const int s = k & 3;
    // tail-exact counted wait: younger stages = min(3, nt-1-k), 4 loads each
    if (k + 3 <= nt - 1) {
      asm volatile("s_waitcnt vmcnt(12)" ::: "memory");
    } else if (k + 2 == nt - 1) {
      asm volatile("s_waitcnt vmcnt(8)" ::: "memory");
    } else if (k + 1 == nt - 1) {
      asm volatile("s_waitcnt vmcnt(4)" ::: "memory");
    } else {
      asm volatile("s_waitcnt vmcnt(0)" ::: "memory");
    }
    __builtin_amdgcn_s_barrier();  // all waves' stage(k) landed

    s16x8 af[8], bf[4];
#pragma unroll
    for (int mf = 0; mf < 8; ++mf) af[mf] = *(const s16x8*)&lA[s][offA[mf]];
#pragma unroll
    for (int nf = 0; nf < 4; ++nf) bf[nf] = *(const s16x8*)&lB[s][offB[nf]];

    __builtin_amdgcn_s_setprio(1);
#pragma unroll
    for (int mf = 0; mf < 8; ++mf)
#pragma unroll
      for (int nf = 0; nf < 4; ++nf)
        acc[mf][nf] = mfma16(af[mf], bf[nf], acc[mf][nf]);
    __builtin_amdgcn_s_setprio(0);

    asm volatile("s_waitcnt lgkmcnt(0)" ::: "memory");
    __builtin_amdgcn_sched_barrier(0);
    __builtin_amdgcn_s_barrier();  // all waves done reading slot s

    if (k + 4 < nt) STAGE(s, k + 4);
  }
#undef STAGE

  const int ccol = n0 + wn * 64 + c;
  float bv[4];
#pragma unroll
  for (int nf = 0; nf < 4; ++nf) bv[nf] = bias[ccol + nf * 16];
#pragma unroll
  for (int mf = 0; mf < 8; ++mf)
#pragma unroll
    for (int r = 0; r < 4; ++r) {
      size_t rowoff = (size_t)(m0 + wm * 128 + mf * 16 + g * 4 + r) * N;
#pragma unroll
      for (int nf = 0; nf < 4; ++nf) {
        float vo = acc[mf][nf][r] + bv[nf];
        if (BF16OUT)
          ((unsigned short*)Cv)[rowoff + ccol + nf * 16] = f2bf(vo);
        else
          ((float*)Cv)[rowoff + ccol + nf * 16] = vo;
      }
    }
}

// -------- 128x128 bf16 GEMM, BK=64 deep pipeline (proj; right shape for N=1280) ----
template<int BF16OUT>
__global__ __launch_bounds__(256, 2) void gemm128_kernel(const unsigned short* __restrict__ A,
                                                         const unsigned short* __restrict__ B,
                                                         const float* __restrict__ bias,
                                                         void* __restrict__ Cv,
                                                         int M, int N, int K,
                                                         int gx, int gy) {
  __shared__ __attribute__((aligned(16))) unsigned short lA[2][128 * 64];
  __shared__ __attribute__((aligned(16))) unsigned short lB[2][128 * 64];
  const int t = threadIdx.x;
  const int lane = t & 63, g = lane >> 4, c = lane & 15, cx = c & 7;
  const int w = t >> 6, wm = w >> 1, wn = w & 1;

  int nwg = gx * gy;
  int bid = blockIdx.x;
  int cpx = nwg >> 3;
  int swz = (bid & 7) * cpx + (bid >> 3);
  const int m0 = (swz / gx) * 128, n0 = (swz % gx) * 128;
  const int nt = K >> 6;

  const unsigned short* aS[4];
  const unsigned short* bS[4];
#pragma unroll
  for (int i = 0; i < 4; ++i) {
    int ch = t + i * 256;
    int row = ch >> 3, slot = ch & 7;
    int qsrc = slot ^ (row & 7);
    aS[i] = A + (size_t)(m0 + row) * K + qsrc * 8;
    bS[i] = B + (size_t)(n0 + row) * K + qsrc * 8;
  }

#define STAGE(buf, kt)                                      \
  do {                                                      \
    int _ko = (kt) * 64;                                    \
    gload16(aS[0] + _ko, &lA[buf][(t) * 8]);                \
    gload16(aS[1] + _ko, &lA[buf][(t + 256) * 8]);          \
    gload16(aS[2] + _ko, &lA[buf][(t + 512) * 8]);          \
    gload16(aS[3] + _ko, &lA[buf][(t + 768) * 8]);          \
    gload16(bS[0] + _ko, &lB[buf][(t) * 8]);                \
    gload16(bS[1] + _ko, &lB[buf][(t + 256) * 8]);          \
    gload16(bS[2] + _ko, &lB[buf][(t + 512) * 8]);          \
    gload16(bS[3] + _ko, &lB[buf][(t + 768) * 8]);          \
  } while (0)

  const f32x4 fz = {0.f, 0.f, 0.f, 0.f};
  f32x4 acc[4][4];
#pragma unroll
  for (int i = 0; i < 4; ++i)
#pragma unroll
    for (int j = 0; j < 4; ++j) acc[i][j] = fz;

  STAGE(0, 0);
  STAGE(1, 1);

  for (int k = 0; k < nt; ++k) {
    const int b = k & 1;
    if (k + 1 < nt) {
      asm volatile("s_waitcnt vmcnt(16)" ::: "memory");
    } else {
      asm volatile("s_waitcnt vmcnt(0)" ::: "memory");
    }
    __builtin_amdgcn_s_barrier();

    s16x8 af0[4], af1[4], bf0[4], bf1[4];
#pragma unroll
    for (int mf = 0; mf < 4; ++mf) {
      const unsigned short* rp = &lA[b][(wm * 64 + mf * 16 + c) * 64];
      af0[mf] = *(const s16x8*)(rp + (g ^ cx) * 8);
      af1[mf] = *(const s16x8*)(rp + ((4 ^ g ^ cx) * 8));
    }
#pragma unroll
    for (int nf = 0; nf < 4; ++nf) {
      const unsigned short* rp = &lB[b][(wn * 64 + nf * 16 + c) * 64];
      bf0[nf] = *(const s16x8*)(rp + (g ^ cx) * 8);
      bf1[nf] = *(const s16x8*)(rp + ((4 ^ g ^ cx) * 8));
    }

    __builtin_amdgcn_s_setprio(1);
#pragma unroll
    for (int mf = 0; mf < 4; ++mf)
#pragma unroll
      for (int nf = 0; nf < 4; ++nf)
        acc[mf][nf] = mfma16(af0[mf], bf0[nf], acc[mf][nf]);
    __builtin_amdgcn_s_setprio(0);

    asm volatile("s_waitcnt lgkmcnt(0)" ::: "memory");
    __builtin_amdgcn_sched_barrier(0);
    __builtin_amdgcn_s_barrier();

    if (k + 2 < nt) STAGE(b, k + 2);
    __builtin_amdgcn_sched_barrier(0);

    __builtin_amdgcn_s_setprio(1);
#pragma unroll
    for (int mf = 0; mf < 4; ++mf)
#pragma unroll
      for (int nf = 0; nf < 4; ++nf)
        acc[mf][nf] = mfma16(af1[mf], bf1[nf], acc[mf][nf]);
    __builtin_amdgcn_s_setprio(0);
  }
#undef STAGE

  const int ccol = n0 + wn * 64 + c;
  float bv[4];
#pragma unroll
  for (int nf = 0; nf < 4; ++nf) bv[nf] = bias[ccol + nf * 16];
#pragma unroll
  for (int mf = 0; mf < 4; ++mf)
#pragma unroll
    for (int r = 0; r < 4; ++r) {
      size_t rowoff = (size_t)(m0 + wm * 64 + mf * 16 + g * 4 + r) * N;
#pragma unroll
      for (int nf = 0; nf < 4; ++nf) {
        float vo = acc[mf][nf][r] + bv[nf];
        if (BF16OUT)
          ((unsigned short*)Cv)[rowoff + ccol + nf * 16] = f2bf(vo);
        else
          ((float*)Cv)[rowoff + ccol + nf * 16] = vo;
      }
    }
}

// ---------------- RoPE + QKV split + V transpose ----------------
__global__ __launch_bounds__(256) void rope_split_kernel(const unsigned short* __restrict__ qkv,
                                                         const float* __restrict__ cosT,
                                                         const float* __restrict__ sinT,
                                                         unsigned short* __restrict__ Qb,
                                                         unsigned short* __restrict__ Kb,
                                                         unsigned short* __restrict__ Vt) {
  __shared__ unsigned short vls[80][66];
  const int t = threadIdx.x;
  const int s0 = blockIdx.x * 64, h = blockIdx.y;

  for (int it = t; it < 64 * 10 * 2; it += 256) {
    int qk = it & 1;
    int jj = (it >> 1) % 10;
    int row = (it >> 1) / 10;
    int s = s0 + row;
    const unsigned short* src = qkv + (size_t)s * N3 + h * 240 + qk * 80;
    unsigned short* dst = (qk ? Kb : Qb) + ((size_t)h * S_LEN + s) * HDIM;
    int d0 = jj * 4;
    s16x4 a = *(const s16x4*)(src + d0);
    s16x4 b = *(const s16x4*)(src + 40 + d0);
    float4 cs = *(const float4*)(cosT + s * 40 + d0);
    float4 sn = *(const float4*)(sinT + s * 40 + d0);
    float sc = qk ? 1.f : (QSCALE * LOG2E);
    float ca[4] = {cs.x, cs.y, cs.z, cs.w};
    float sa[4] = {sn.x, sn.y, sn.z, sn.w};
    s16x4 o1, o2;
#pragma unroll
    for (int i = 0; i < 4; ++i) {
      float q1 = bf2f((unsigned short)a[i]);
      float q2 = bf2f((unsigned short)b[i]);
      o1[i] = (short)f2bf((q1 * ca[i] - q2 * sa[i]) * sc);
      o2[i] = (short)f2bf((q2 * ca[i] + q1 * sa[i]) * sc);
    }
    *(s16x4*)(dst + d0) = o1;
    *(s16x4*)(dst + 40 + d0) = o2;
  }

  for (int it = t; it < 640; it += 256) {
    int row = it / 10, c8 = it % 10;
    int s = s0 + row;
    s16x8 v = *(const s16x8*)(qkv + (size_t)s * N3 + h * 240 + 160 + c8 * 8);
#pragma unroll
    for (int i = 0; i < 8; ++i) vls[c8 * 8 + i][row] = (unsigned short)v[i];
  }
  __syncthreads();
  for (int it = t; it < 640; it += 256) {
    int d = it / 8, s8 = it % 8;
    s16x8 v;
#pragma unroll
    for (int i = 0; i < 8; ++i) v[i] = (short)vls[d][s8 * 8 + i];
    *(s16x8*)(Vt + (((size_t)h * 64 + (s0 >> 6)) * 80 + d) * 64 + s8 * 8) = v;
  }
}

// ---------------- flash attention, 32x32 swapped-QK^T, P-in-register ----------------
__global__ __launch_bounds__(128, 2) void attn_kernel(const unsigned short* __restrict__ Qb,
                                                      const unsigned short* __restrict__ Kb,
                                                      const unsigned short* __restrict__ Vt,
                                                      const int* __restrict__ cu, int ncu,
                                                      unsigned short* __restrict__ ctx) {
  __shared__ __attribute__((aligned(16))) unsigned short Kl[64 * 128];
  __shared__ __attribute__((aligned(16))) unsigned short Vl[80 * 128];
  const int t = threadIdx.x, lane = t & 63, w = t >> 6;
  const int cq = lane & 31, hi = lane >> 5;

  const int bid = blockIdx.x;
  const int r_ = bid & 7, qi = (bid >> 3) & 15, u = bid >> 7;
  const int grp = u * 8 + r_;
  const int h = grp >> 2, qc = grp & 3;
  const int q0 = qc * 1024 + qi * 64;
  const int nseg = ncu - 1;

  int qlo = 0, qhi = 0, ks = 0, ke = 0, wlo = 0, whi = 0, wlo2 = 0;
  const int myq = q0 + w * 32 + cq;
  const int wr0 = q0 + w * 32, wr1 = wr0 + 31;
  for (int i = 0; i < nseg; ++i) {
    int a = cu[i], b = cu[i + 1];
    if (myq >= a && myq < b) { qlo = a; qhi = b; }
    if (wr0 >= a && wr0 < b) { wlo = a; whi = b; }
    if (wr1 >= a && wr1 < b) { wlo2 = a; }
    if (q0 >= a && q0 < b) ks = a;
    if (q0 + 63 >= a && q0 + 63 < b) ke = b;
  }
  const bool uniform = (wlo == wlo2);
  const int k_begin = ks & ~63;

  s16x8 qf[5];
  {
    const unsigned short* qp = Qb + ((size_t)h * S_LEN + q0 + w * 32 + cq) * HDIM + hi * 8;
#pragma unroll
    for (int kk = 0; kk < 5; ++kk) qf[kk] = *(const s16x8*)(qp + kk * 16);
  }

  int kA[5], vA[5], kO[5], vO[5];
#pragma unroll
  for (int i = 0; i < 5; ++i) {
    int ch = t + i * 128;
    int kr = ch / 10, kc = ch % 10;
    kA[i] = kr * 128 + ((kc ^ (kr & 15)) << 3);
    kO[i] = ch * 8;
    int vd = ch >> 3, vk = ch & 7;
    vA[i] = vd * 128 + ((vk ^ (vd & 15)) << 3);
    vO[i] = ch * 8;
  }
  const unsigned short* kcur = Kb + (size_t)h * S_LEN * HDIM + (size_t)k_begin * HDIM;
  const unsigned short* vcur = Vt + ((size_t)h * 64 + (k_begin >> 6)) * 5120;

  s16x8 onesf;
#pragma unroll
  for (int i = 0; i < 8; ++i) onesf[i] = (short)(unsigned short)0x3F80;

  const f32x16 z16 = {0.f,0.f,0.f,0.f,0.f,0.f,0.f,0.f,0.f,0.f,0.f,0.f,0.f,0.f,0.f,0.f};
  f32x16 o0 = z16, o1 = z16, o2 = z16;

  s16x8 kreg[5], vreg[5];
#pragma unroll
  for (int i = 0; i < 5; ++i) {
    kreg[i] = *(const s16x8*)(kcur + kO[i]);
    vreg[i] = *(const s16x8*)(vcur + vO[i]);
  }

  for (int k0 = k_begin; k0 < ke; k0 += 64) {
    __syncthreads();
#pragma unroll
    for (int i = 0; i < 5; ++i) {
      *(s16x8*)&Kl[kA[i]] = kreg[i];
      *(s16x8*)&Vl[vA[i]] = vreg[i];
    }
    if (k0 + 64 < ke) {
      kcur += 5120; vcur += 5120;
#pragma unroll
      for (int i = 0; i < 5; ++i) {
        kreg[i] = *(const s16x8*)(kcur + kO[i]);
        vreg[i] = *(const s16x8*)(vcur + vO[i]);
      }
    }
    __syncthreads();

    f32x16 sc0 = z16, sc1 = z16;
#pragma unroll
    for (int kk = 0; kk < 5; ++kk) {
      const int cb = ((2 * kk + hi) ^ (cq & 15)) << 3;
      s16x8 kf0 = *(const s16x8*)&Kl[cq * 128 + cb];
      s16x8 kf1 = *(const s16x8*)&Kl[(32 + cq) * 128 + cb];
      sc0 = mfma32(kf0, qf[kk], sc0);
      sc1 = mfma32(kf1, qf[kk], sc1);
    }

    if (!(uniform && k0 >= wlo && k0 + 64 <= whi)) {
#pragma unroll
      for (int r = 0; r < 16; ++r) {
        int key0 = k0 + (r & 3) + 8 * (r >> 2) + 4 * hi;
        int key1 = key0 + 32;
        sc0[r] = (key0 >= qlo && key0 < qhi) ? sc0[r] : -3e38f;
        sc1[r] = (key1 >= qlo && key1 < qhi) ? sc1[r] : -3e38f;
      }
    }

    float pv0[16], pv1[16];
#pragma unroll
    for (int r = 0; r < 16; ++r) {
      pv0[r] = fexp2(sc0[r]);
      pv1[r] = fexp2(sc1[r]);
    }

    unsigned pk0[4][2], pk1[4][2];
#pragma unroll
    for (int q8 = 0; q8 < 4; ++q8)
#pragma unroll
      for (int i = 0; i < 2; ++i) {
        pk0[q8][i] = cvtpk_bf16(pv0[4 * q8 + 2 * i], pv0[4 * q8 + 2 * i + 1]);
        pk1[q8][i] = cvtpk_bf16(pv1[4 * q8 + 2 * i], pv1[4 * q8 + 2 * i + 1]);
      }

#pragma unroll
    for (int kk = 0; kk < 4; ++kk) {
      const int e = (kk & 1) * 2;
      unsigned a0, a1, b0, b1;
      if (kk < 2) { a0 = pk0[e][0]; b0 = pk0[e + 1][0]; a1 = pk0[e][1]; b1 = pk0[e + 1][1]; }
      else        { a0 = pk1[e][0]; b0 = pk1[e + 1][0]; a1 = pk1[e][1]; b1 = pk1[e + 1][1]; }
      auto s0 = __builtin_amdgcn_permlane32_swap(a0, b0, false, false);
      auto s1 = __builtin_amdgcn_permlane32_swap(a1, b1, false, false);
      union { unsigned u[4]; s16x8 v; } fr_;
      fr_.u[0] = s0[0]; fr_.u[1] = s1[0]; fr_.u[2] = s0[1]; fr_.u[3] = s1[1];
      const int cb = ((2 * kk + hi) ^ (cq & 15)) << 3;
      s16x8 vf0 = *(const s16x8*)&Vl[cq * 128 + cb];
      s16x8 vf1 = *(const s16x8*)&Vl[(32 + cq) * 128 + cb];
      s16x8 vf2 = (cq < 16) ? *(const s16x8*)&Vl[(64 + cq) * 128 + cb] : onesf;
      o0 = mfma32(fr_.v, vf0, o0);
      o1 = mfma32(fr_.v, vf1, o1);
      o2 = mfma32(fr_.v, vf2, o2);
    }
  }

#pragma unroll
  for (int r = 0; r < 16; ++r) {
    float lsum = __shfl(o2[r], 16 | (lane & 32));
    float inv = (lsum > 0.f) ? 1.f / lsum : 0.f;
    const int crow = (r & 3) + 8 * (r >> 2) + 4 * hi;
    int srow = q0 + w * 32 + crow;
    size_t base = (size_t)srow * EMB + h * HDIM;
    ctx[base + cq] = f2bf(o0[r] * inv);
    ctx[base + 32 + cq] = f2bf(o1[r] * inv);
    if (cq < 16) ctx[base + 64 + cq] = f2bf(o2[r] * inv);
  }
}

// ---------------- launch ----------------
extern "C" void kernel_launch(void* const* d_in, const int* in_sizes, int n_in,
                              void* d_out, int out_size, void* d_ws, size_t ws_size,
                              hipStream_t stream) {
  const float* x      = (const float*)d_in[0];
  const int*   cu     = (const int*)d_in[1];
  const float* rope   = (const float*)d_in[2];
  const float* w_qkv  = (const float*)d_in[3];
  const float* b_qkv  = (const float*)d_in[4];
  const float* w_proj = (const float*)d_in[5];
  const float* b_proj = (const float*)d_in[6];
  float* out = (float*)d_out;
  const int ncu = in_sizes[1];

  char* ws = (char*)d_ws;
  unsigned short* xb     = (unsigned short*)(ws + 0);          // 10485760 B
  unsigned short* wqkvb  = (unsigned short*)(ws + 10485760);   // 9830400 B
  unsigned short* wprojb = (unsigned short*)(ws + 20316160);   // 3276800 B
  float*          cosT   = (float*)(ws + 23592960);            // 655360 B
  float*          sinT   = (float*)(ws + 24248320);            // 655360 B
  unsigned short* qkvb   = (unsigned short*)(ws + 24903680);   // 31457280 B
  unsigned short* Qb     = (unsigned short*)(ws + 56360960);   // 10485760 B ([H][S][80])
  unsigned short* Kb     = (unsigned short*)(ws + 68943872);   // 10485760 B
  unsigned short* Vt     = (unsigned short*)(ws + 81526784);   // 10485760 B (tiled)
  unsigned short* ctxb   = (unsigned short*)(ws + 92012544);   // 10485760 B

  cvt_kernel<<<5120, 256, 0, stream>>>(x, xb, 1310720);
  cvt_kernel<<<4800, 256, 0, stream>>>(w_qkv, wqkvb, 1228800);
  cvt_kernel<<<1600, 256, 0, stream>>>(w_proj, wprojb, 409600);
  rope_tab_kernel<<<640, 256, 0, stream>>>(rope, cosT, sinT, 163840);

  gemm256_kernel<1><<<240, 512, 0, stream>>>(xb, wqkvb, b_qkv, (void*)qkvb,
                                             4096, 3840, 1280, 15, 16);
  rope_split_kernel<<<dim3(64, 16), 256, 0, stream>>>(qkvb, cosT, sinT, Qb, Kb, Vt);
  attn_kernel<<<1024, 128, 0, stream>>>(Qb, Kb, Vt, cu, ncu, ctxb);
  gemm128_kernel<0><<<320, 256, 0, stream>>>(ctxb, wprojb, b_proj, (void*)out,
                                             4096, 1280, 1280, 10, 32);
}

// Round 17
// 128.716 us; speedup vs baseline: 1.1332x; 1.1332x over previous
//
#include <hip/hip_runtime.h>
#include <hip/hip_bf16.h>
#include <stdint.h>
#include <stddef.h>

#define S_LEN 4096
#define EMB   1280
#define NH    16
#define HDIM  80
#define N3    3840
#define QSCALE 0.11180339887498949f   // 1/sqrt(80)
#define LOG2E  1.4426950408889634f

typedef __attribute__((ext_vector_type(4))) float f32x4;
typedef __attribute__((ext_vector_type(16))) float f32x16;
typedef __attribute__((ext_vector_type(4))) short s16x4;
typedef __attribute__((ext_vector_type(8))) short s16x8;
typedef __attribute__((ext_vector_type(8))) __bf16 bf16x8;

typedef __attribute__((address_space(1))) const unsigned int as1_u32;
typedef __attribute__((address_space(3))) unsigned int as3_u32;

__device__ __forceinline__ unsigned short f2bf(float f) {
  return __builtin_bit_cast(unsigned short, __float2bfloat16(f));
}
__device__ __forceinline__ float bf2f(unsigned short b) {
  union { unsigned int u; float f; } v; v.u = ((unsigned int)b) << 16;
  return v.f;
}

__device__ __forceinline__ f32x4 mfma16(s16x8 a, s16x8 b, f32x4 c) {
  return __builtin_amdgcn_mfma_f32_16x16x32_bf16(
      __builtin_bit_cast(bf16x8, a), __builtin_bit_cast(bf16x8, b), c, 0, 0, 0);
}
__device__ __forceinline__ f32x16 mfma32(s16x8 a, s16x8 b, f32x16 c) {
  return __builtin_amdgcn_mfma_f32_32x32x16_bf16(
      __builtin_bit_cast(bf16x8, a), __builtin_bit_cast(bf16x8, b), c, 0, 0, 0);
}

__device__ __forceinline__ unsigned cvtpk_bf16(float a, float b) {
  unsigned r;
  asm("v_cvt_pk_bf16_f32 %0, %1, %2" : "=v"(r) : "v"(a), "v"(b));
  return r;
}

// raw hardware exp2
__device__ __forceinline__ float fexp2(float x) {
  float r;
  asm("v_exp_f32 %0, %1" : "=v"(r) : "v"(x));
  return r;
}

__device__ __forceinline__ void gload16(const void* g, void* l) {
  __builtin_amdgcn_global_load_lds((as1_u32*)g, (as3_u32*)l, 16, 0, 0);
}

// ------- fused preprocessing: 3x f32->bf16 convert + rope sincos table -------
// items [0,1310720)            : x float4 convert
// items [1310720,2539520)      : w_qkv float4 convert
// items [2539520,2949120)      : w_proj float4 convert
// items [2949120,3112960)      : rope scalar sincos
__global__ __launch_bounds__(256) void fused_pre_kernel(const float* __restrict__ x,
                                                        const float* __restrict__ wq,
                                                        const float* __restrict__ wp,
                                                        const float* __restrict__ rope,
                                                        unsigned short* __restrict__ xb,
                                                        unsigned short* __restrict__ wqb,
                                                        unsigned short* __restrict__ wpb,
                                                        float* __restrict__ cosT,
                                                        float* __restrict__ sinT) {
  int i = blockIdx.x * 256 + threadIdx.x;
  const float* src;
  unsigned short* dst;
  int j;
  if (i < 1310720) { src = x; dst = xb; j = i; }
  else if (i < 2539520) { src = wq; dst = wqb; j = i - 1310720; }
  else if (i < 2949120) { src = wp; dst = wpb; j = i - 2539520; }
  else {
    int j2 = i - 2949120;
    if (j2 < 163840) {
      float v = rope[j2];
      float s, c;
      sincosf(v, &s, &c);
      cosT[j2] = c; sinT[j2] = s;
    }
    return;
  }
  float4 v = ((const float4*)src)[j];
  s16x4 o;
  o[0] = (short)f2bf(v.x); o[1] = (short)f2bf(v.y);
  o[2] = (short)f2bf(v.z); o[3] = (short)f2bf(v.w);
  ((s16x4*)dst)[j] = o;
}

// ---------------- 256x256 bf16 GEMM, BK=64, deep pipeline (QKV) ----------------
// Proven round-15 version: 2 barriers per K-64 tile, vmcnt(16) counted wait.
template<int BF16OUT>
__global__ __launch_bounds__(512, 2) void gemm256_kernel(const unsigned short* __restrict__ A,
                                                         const unsigned short* __restrict__ B,
                                                         const float* __restrict__ bias,
                                                         void* __restrict__ Cv,
                                                         int M, int N, int K,
                                                         int gx, int gy) {
  __shared__ __attribute__((aligned(16))) unsigned short lA[2][256 * 64];
  __shared__ __attribute__((aligned(16))) unsigned short lB[2][256 * 64];
  const int t = threadIdx.x;
  const int lane = t & 63, g = lane >> 4, c = lane & 15, cx = c & 7;
  const int w = t >> 6, wm = w >> 2, wn = w & 3;

  int nwg = gx * gy;
  int bid = blockIdx.x;
  int cpx = nwg >> 3;
  int swz = (bid & 7) * cpx + (bid >> 3);
  const int m0 = (swz / gx) * 256, n0 = (swz % gx) * 256;
  const int nt = K >> 6;

  const unsigned short* aS[4];
  const unsigned short* bS[4];
#pragma unroll
  for (int i = 0; i < 4; ++i) {
    int ch = t + i * 512;
    int row = ch >> 3, slot = ch & 7;
    int qsrc = slot ^ (row & 7);
    aS[i] = A + (size_t)(m0 + row) * K + qsrc * 8;
    bS[i] = B + (size_t)(n0 + row) * K + qsrc * 8;
  }

#define STAGE(buf, kt)                                      \
  do {                                                      \
    int _ko = (kt) * 64;                                    \
    gload16(aS[0] + _ko, &lA[buf][(t) * 8]);                \
    gload16(aS[1] + _ko, &lA[buf][(t + 512) * 8]);          \
    gload16(aS[2] + _ko, &lA[buf][(t + 1024) * 8]);         \
    gload16(aS[3] + _ko, &lA[buf][(t + 1536) * 8]);         \
    gload16(bS[0] + _ko, &lB[buf][(t) * 8]);                \
    gload16(bS[1] + _ko, &lB[buf][(t + 512) * 8]);          \
    gload16(bS[2] + _ko, &lB[buf][(t + 1024) * 8]);         \
    gload16(bS[3] + _ko, &lB[buf][(t + 1536) * 8]);         \
  } while (0)

  const f32x4 fz = {0.f, 0.f, 0.f, 0.f};
  f32x4 acc[8][4];
#pragma unroll
  for (int i = 0; i < 8; ++i)
#pragma unroll
    for (int j = 0; j < 4; ++j) acc[i][j] = fz;

  STAGE(0, 0);
  STAGE(1, 1);

  for (int k = 0; k < nt; ++k) {
    const int b = k & 1;
    if (k + 1 < nt) {
      asm volatile("s_waitcnt vmcnt(16)" ::: "memory");
    } else {
      asm volatile("s_waitcnt vmcnt(0)" ::: "memory");
    }
    __builtin_amdgcn_s_barrier();  // B1: buf b fully staged

    s16x8 af0[8], af1[8], bf0[4], bf1[4];
#pragma unroll
    for (int mf = 0; mf < 8; ++mf) {
      const unsigned short* rp = &lA[b][(wm * 128 + mf * 16 + c) * 64];
      af0[mf] = *(const s16x8*)(rp + (g ^ cx) * 8);
      af1[mf] = *(const s16x8*)(rp + ((4 ^ g ^ cx) * 8));
    }
#pragma unroll
    for (int nf = 0; nf < 4; ++nf) {
      const unsigned short* rp = &lB[b][(wn * 64 + nf * 16 + c) * 64];
      bf0[nf] = *(const s16x8*)(rp + (g ^ cx) * 8);
      bf1[nf] = *(const s16x8*)(rp + ((4 ^ g ^ cx) * 8));
    }

    __builtin_amdgcn_s_setprio(1);
#pragma unroll
    for (int mf = 0; mf < 8; ++mf)
#pragma unroll
      for (int nf = 0; nf < 4; ++nf)
        acc[mf][nf] = mfma16(af0[mf], bf0[nf], acc[mf][nf]);
    __builtin_amdgcn_s_setprio(0);

    asm volatile("s_waitcnt lgkmcnt(0)" ::: "memory");
    __builtin_amdgcn_sched_barrier(0);
    __builtin_amdgcn_s_barrier();  // B2: all waves done reading buf b

    if (k + 2 < nt) STAGE(b, k + 2);
    __builtin_amdgcn_sched_barrier(0);

    __builtin_amdgcn_s_setprio(1);
#pragma unroll
    for (int mf = 0; mf < 8; ++mf)
#pragma unroll
      for (int nf = 0; nf < 4; ++nf)
        acc[mf][nf] = mfma16(af1[mf], bf1[nf], acc[mf][nf]);
    __builtin_amdgcn_s_setprio(0);
  }
#undef STAGE

  const int ccol = n0 + wn * 64 + c;
  float bv[4];
#pragma unroll
  for (int nf = 0; nf < 4; ++nf) bv[nf] = bias[ccol + nf * 16];
#pragma unroll
  for (int mf = 0; mf < 8; ++mf)
#pragma unroll
    for (int r = 0; r < 4; ++r) {
      size_t rowoff = (size_t)(m0 + wm * 128 + mf * 16 + g * 4 + r) * N;
#pragma unroll
      for (int nf = 0; nf < 4; ++nf) {
        float vo = acc[mf][nf][r] + bv[nf];
        if (BF16OUT)
          ((unsigned short*)Cv)[rowoff + ccol + nf * 16] = f2bf(vo);
        else
          ((float*)Cv)[rowoff + ccol + nf * 16] = vo;
      }
    }
}

// -------- 128x128 bf16 GEMM, BK=64 deep pipeline (proj; right shape for N=1280) ----
template<int BF16OUT>
__global__ __launch_bounds__(256, 2) void gemm128_kernel(const unsigned short* __restrict__ A,
                                                         const unsigned short* __restrict__ B,
                                                         const float* __restrict__ bias,
                                                         void* __restrict__ Cv,
                                                         int M, int N, int K,
                                                         int gx, int gy) {
  __shared__ __attribute__((aligned(16))) unsigned short lA[2][128 * 64];
  __shared__ __attribute__((aligned(16))) unsigned short lB[2][128 * 64];
  const int t = threadIdx.x;
  const int lane = t & 63, g = lane >> 4, c = lane & 15, cx = c & 7;
  const int w = t >> 6, wm = w >> 1, wn = w & 1;

  int nwg = gx * gy;
  int bid = blockIdx.x;
  int cpx = nwg >> 3;
  int swz = (bid & 7) * cpx + (bid >> 3);
  const int m0 = (swz / gx) * 128, n0 = (swz % gx) * 128;
  const int nt = K >> 6;

  const unsigned short* aS[4];
  const unsigned short* bS[4];
#pragma unroll
  for (int i = 0; i < 4; ++i) {
    int ch = t + i * 256;
    int row = ch >> 3, slot = ch & 7;
    int qsrc = slot ^ (row & 7);
    aS[i] = A + (size_t)(m0 + row) * K + qsrc * 8;
    bS[i] = B + (size_t)(n0 + row) * K + qsrc * 8;
  }

#define STAGE(buf, kt)                                      \
  do {                                                      \
    int _ko = (kt) * 64;                                    \
    gload16(aS[0] + _ko, &lA[buf][(t) * 8]);                \
    gload16(aS[1] + _ko, &lA[buf][(t + 256) * 8]);          \
    gload16(aS[2] + _ko, &lA[buf][(t + 512) * 8]);          \
    gload16(aS[3] + _ko, &lA[buf][(t + 768) * 8]);          \
    gload16(bS[0] + _ko, &lB[buf][(t) * 8]);                \
    gload16(bS[1] + _ko, &lB[buf][(t + 256) * 8]);          \
    gload16(bS[2] + _ko, &lB[buf][(t + 512) * 8]);          \
    gload16(bS[3] + _ko, &lB[buf][(t + 768) * 8]);          \
  } while (0)

  const f32x4 fz = {0.f, 0.f, 0.f, 0.f};
  f32x4 acc[4][4];
#pragma unroll
  for (int i = 0; i < 4; ++i)
#pragma unroll
    for (int j = 0; j < 4; ++j) acc[i][j] = fz;

  STAGE(0, 0);
  STAGE(1, 1);

  for (int k = 0; k < nt; ++k) {
    const int b = k & 1;
    if (k + 1 < nt) {
      asm volatile("s_waitcnt vmcnt(16)" ::: "memory");
    } else {
      asm volatile("s_waitcnt vmcnt(0)" ::: "memory");
    }
    __builtin_amdgcn_s_barrier();

    s16x8 af0[4], af1[4], bf0[4], bf1[4];
#pragma unroll
    for (int mf = 0; mf < 4; ++mf) {
      const unsigned short* rp = &lA[b][(wm * 64 + mf * 16 + c) * 64];
      af0[mf] = *(const s16x8*)(rp + (g ^ cx) * 8);
      af1[mf] = *(const s16x8*)(rp + ((4 ^ g ^ cx) * 8));
    }
#pragma unroll
    for (int nf = 0; nf < 4; ++nf) {
      const unsigned short* rp = &lB[b][(wn * 64 + nf * 16 + c) * 64];
      bf0[nf] = *(const s16x8*)(rp + (g ^ cx) * 8);
      bf1[nf] = *(const s16x8*)(rp + ((4 ^ g ^ cx) * 8));
    }

    __builtin_amdgcn_s_setprio(1);
#pragma unroll
    for (int mf = 0; mf < 4; ++mf)
#pragma unroll
      for (int nf = 0; nf < 4; ++nf)
        acc[mf][nf] = mfma16(af0[mf], bf0[nf], acc[mf][nf]);
    __builtin_amdgcn_s_setprio(0);

    asm volatile("s_waitcnt lgkmcnt(0)" ::: "memory");
    __builtin_amdgcn_sched_barrier(0);
    __builtin_amdgcn_s_barrier();

    if (k + 2 < nt) STAGE(b, k + 2);
    __builtin_amdgcn_sched_barrier(0);

    __builtin_amdgcn_s_setprio(1);
#pragma unroll
    for (int mf = 0; mf < 4; ++mf)
#pragma unroll
      for (int nf = 0; nf < 4; ++nf)
        acc[mf][nf] = mfma16(af1[mf], bf1[nf], acc[mf][nf]);
    __builtin_amdgcn_s_setprio(0);
  }
#undef STAGE

  const int ccol = n0 + wn * 64 + c;
  float bv[4];
#pragma unroll
  for (int nf = 0; nf < 4; ++nf) bv[nf] = bias[ccol + nf * 16];
#pragma unroll
  for (int mf = 0; mf < 4; ++mf)
#pragma unroll
    for (int r = 0; r < 4; ++r) {
      size_t rowoff = (size_t)(m0 + wm * 64 + mf * 16 + g * 4 + r) * N;
#pragma unroll
      for (int nf = 0; nf < 4; ++nf) {
        float vo = acc[mf][nf][r] + bv[nf];
        if (BF16OUT)
          ((unsigned short*)Cv)[rowoff + ccol + nf * 16] = f2bf(vo);
        else
          ((float*)Cv)[rowoff + ccol + nf * 16] = vo;
      }
    }
}

// ---------------- RoPE + QKV split + V transpose ----------------
__global__ __launch_bounds__(256) void rope_split_kernel(const unsigned short* __restrict__ qkv,
                                                         const float* __restrict__ cosT,
                                                         const float* __restrict__ sinT,
                                                         unsigned short* __restrict__ Qb,
                                                         unsigned short* __restrict__ Kb,
                                                         unsigned short* __restrict__ Vt) {
  __shared__ unsigned short vls[80][66];
  const int t = threadIdx.x;
  const int s0 = blockIdx.x * 64, h = blockIdx.y;

  for (int it = t; it < 64 * 10 * 2; it += 256) {
    int qk = it & 1;
    int jj = (it >> 1) % 10;
    int row = (it >> 1) / 10;
    int s = s0 + row;
    const unsigned short* src = qkv + (size_t)s * N3 + h * 240 + qk * 80;
    unsigned short* dst = (qk ? Kb : Qb) + ((size_t)h * S_LEN + s) * HDIM;
    int d0 = jj * 4;
    s16x4 a = *(const s16x4*)(src + d0);
    s16x4 b = *(const s16x4*)(src + 40 + d0);
    float4 cs = *(const float4*)(cosT + s * 40 + d0);
    float4 sn = *(const float4*)(sinT + s * 40 + d0);
    float sc = qk ? 1.f : (QSCALE * LOG2E);
    float ca[4] = {cs.x, cs.y, cs.z, cs.w};
    float sa[4] = {sn.x, sn.y, sn.z, sn.w};
    s16x4 o1, o2;
#pragma unroll
    for (int i = 0; i < 4; ++i) {
      float q1 = bf2f((unsigned short)a[i]);
      float q2 = bf2f((unsigned short)b[i]);
      o1[i] = (short)f2bf((q1 * ca[i] - q2 * sa[i]) * sc);
      o2[i] = (short)f2bf((q2 * ca[i] + q1 * sa[i]) * sc);
    }
    *(s16x4*)(dst + d0) = o1;
    *(s16x4*)(dst + 40 + d0) = o2;
  }

  for (int it = t; it < 640; it += 256) {
    int row = it / 10, c8 = it % 10;
    int s = s0 + row;
    s16x8 v = *(const s16x8*)(qkv + (size_t)s * N3 + h * 240 + 160 + c8 * 8);
#pragma unroll
    for (int i = 0; i < 8; ++i) vls[c8 * 8 + i][row] = (unsigned short)v[i];
  }
  __syncthreads();
  for (int it = t; it < 640; it += 256) {
    int d = it / 8, s8 = it % 8;
    s16x8 v;
#pragma unroll
    for (int i = 0; i < 8; ++i) v[i] = (short)vls[d][s8 * 8 + i];
    *(s16x8*)(Vt + (((size_t)h * 64 + (s0 >> 6)) * 80 + d) * 64 + s8 * 8) = v;
  }
}

// ---------------- flash attention, 32x32 swapped-QK^T, P-in-register ----------------
__global__ __launch_bounds__(128, 2) void attn_kernel(const unsigned short* __restrict__ Qb,
                                                      const unsigned short* __restrict__ Kb,
                                                      const unsigned short* __restrict__ Vt,
                                                      const int* __restrict__ cu, int ncu,
                                                      unsigned short* __restrict__ ctx) {
  __shared__ __attribute__((aligned(16))) unsigned short Kl[64 * 128];
  __shared__ __attribute__((aligned(16))) unsigned short Vl[80 * 128];
  const int t = threadIdx.x, lane = t & 63, w = t >> 6;
  const int cq = lane & 31, hi = lane >> 5;

  const int bid = blockIdx.x;
  const int r_ = bid & 7, qi = (bid >> 3) & 15, u = bid >> 7;
  const int grp = u * 8 + r_;
  const int h = grp >> 2, qc = grp & 3;
  const int q0 = qc * 1024 + qi * 64;
  const int nseg = ncu - 1;

  int qlo = 0, qhi = 0, ks = 0, ke = 0, wlo = 0, whi = 0, wlo2 = 0;
  const int myq = q0 + w * 32 + cq;
  const int wr0 = q0 + w * 32, wr1 = wr0 + 31;
  for (int i = 0; i < nseg; ++i) {
    int a = cu[i], b = cu[i + 1];
    if (myq >= a && myq < b) { qlo = a; qhi = b; }
    if (wr0 >= a && wr0 < b) { wlo = a; whi = b; }
    if (wr1 >= a && wr1 < b) { wlo2 = a; }
    if (q0 >= a && q0 < b) ks = a;
    if (q0 + 63 >= a && q0 + 63 < b) ke = b;
  }
  const bool uniform = (wlo == wlo2);
  const int k_begin = ks & ~63;

  s16x8 qf[5];
  {
    const unsigned short* qp = Qb + ((size_t)h * S_LEN + q0 + w * 32 + cq) * HDIM + hi * 8;
#pragma unroll
    for (int kk = 0; kk < 5; ++kk) qf[kk] = *(const s16x8*)(qp + kk * 16);
  }

  int kA[5], vA[5], kO[5], vO[5];
#pragma unroll
  for (int i = 0; i < 5; ++i) {
    int ch = t + i * 128;
    int kr = ch / 10, kc = ch % 10;
    kA[i] = kr * 128 + ((kc ^ (kr & 15)) << 3);
    kO[i] = ch * 8;
    int vd = ch >> 3, vk = ch & 7;
    vA[i] = vd * 128 + ((vk ^ (vd & 15)) << 3);
    vO[i] = ch * 8;
  }
  const unsigned short* kcur = Kb + (size_t)h * S_LEN * HDIM + (size_t)k_begin * HDIM;
  const unsigned short* vcur = Vt + ((size_t)h * 64 + (k_begin >> 6)) * 5120;

  s16x8 onesf;
#pragma unroll
  for (int i = 0; i < 8; ++i) onesf[i] = (short)(unsigned short)0x3F80;

  const f32x16 z16 = {0.f,0.f,0.f,0.f,0.f,0.f,0.f,0.f,0.f,0.f,0.f,0.f,0.f,0.f,0.f,0.f};
  f32x16 o0 = z16, o1 = z16, o2 = z16;

  s16x8 kreg[5], vreg[5];
#pragma unroll
  for (int i = 0; i < 5; ++i) {
    kreg[i] = *(const s16x8*)(kcur + kO[i]);
    vreg[i] = *(const s16x8*)(vcur + vO[i]);
  }

  for (int k0 = k_begin; k0 < ke; k0 += 64) {
    __syncthreads();
#pragma unroll
    for (int i = 0; i < 5; ++i) {
      *(s16x8*)&Kl[kA[i]] = kreg[i];
      *(s16x8*)&Vl[vA[i]] = vreg[i];
    }
    if (k0 + 64 < ke) {
      kcur += 5120; vcur += 5120;
#pragma unroll
      for (int i = 0; i < 5; ++i) {
        kreg[i] = *(const s16x8*)(kcur + kO[i]);
        vreg[i] = *(const s16x8*)(vcur + vO[i]);
      }
    }
    __syncthreads();

    f32x16 sc0 = z16, sc1 = z16;
#pragma unroll
    for (int kk = 0; kk < 5; ++kk) {
      const int cb = ((2 * kk + hi) ^ (cq & 15)) << 3;
      s16x8 kf0 = *(const s16x8*)&Kl[cq * 128 + cb];
      s16x8 kf1 = *(const s16x8*)&Kl[(32 + cq) * 128 + cb];
      sc0 = mfma32(kf0, qf[kk], sc0);
      sc1 = mfma32(kf1, qf[kk], sc1);
    }

    if (!(uniform && k0 >= wlo && k0 + 64 <= whi)) {
#pragma unroll
      for (int r = 0; r < 16; ++r) {
        int key0 = k0 + (r & 3) + 8 * (r >> 2) + 4 * hi;
        int key1 = key0 + 32;
        sc0[r] = (key0 >= qlo && key0 < qhi) ? sc0[r] : -3e38f;
        sc1[r] = (key1 >= qlo && key1 < qhi) ? sc1[r] : -3e38f;
      }
    }

    float pv0[16], pv1[16];
#pragma unroll
    for (int r = 0; r < 16; ++r) {
      pv0[r] = fexp2(sc0[r]);
      pv1[r] = fexp2(sc1[r]);
    }

    unsigned pk0[4][2], pk1[4][2];
#pragma unroll
    for (int q8 = 0; q8 < 4; ++q8)
#pragma unroll
      for (int i = 0; i < 2; ++i) {
        pk0[q8][i] = cvtpk_bf16(pv0[4 * q8 + 2 * i], pv0[4 * q8 + 2 * i + 1]);
        pk1[q8][i] = cvtpk_bf16(pv1[4 * q8 + 2 * i], pv1[4 * q8 + 2 * i + 1]);
      }

#pragma unroll
    for (int kk = 0; kk < 4; ++kk) {
      const int e = (kk & 1) * 2;
      unsigned a0, a1, b0, b1;
      if (kk < 2) { a0 = pk0[e][0]; b0 = pk0[e + 1][0]; a1 = pk0[e][1]; b1 = pk0[e + 1][1]; }
      else        { a0 = pk1[e][0]; b0 = pk1[e + 1][0]; a1 = pk1[e][1]; b1 = pk1[e + 1][1]; }
      auto s0 = __builtin_amdgcn_permlane32_swap(a0, b0, false, false);
      auto s1 = __builtin_amdgcn_permlane32_swap(a1, b1, false, false);
      union { unsigned u[4]; s16x8 v; } fr_;
      fr_.u[0] = s0[0]; fr_.u[1] = s1[0]; fr_.u[2] = s0[1]; fr_.u[3] = s1[1];
      const int cb = ((2 * kk + hi) ^ (cq & 15)) << 3;
      s16x8 vf0 = *(const s16x8*)&Vl[cq * 128 + cb];
      s16x8 vf1 = *(const s16x8*)&Vl[(32 + cq) * 128 + cb];
      s16x8 vf2 = (cq < 16) ? *(const s16x8*)&Vl[(64 + cq) * 128 + cb] : onesf;
      o0 = mfma32(fr_.v, vf0, o0);
      o1 = mfma32(fr_.v, vf1, o1);
      o2 = mfma32(fr_.v, vf2, o2);
    }
  }

#pragma unroll
  for (int r = 0; r < 16; ++r) {
    float lsum = __shfl(o2[r], 16 | (lane & 32));
    float inv = (lsum > 0.f) ? 1.f / lsum : 0.f;
    const int crow = (r & 3) + 8 * (r >> 2) + 4 * hi;
    int srow = q0 + w * 32 + crow;
    size_t base = (size_t)srow * EMB + h * HDIM;
    ctx[base + cq] = f2bf(o0[r] * inv);
    ctx[base + 32 + cq] = f2bf(o1[r] * inv);
    if (cq < 16) ctx[base + 64 + cq] = f2bf(o2[r] * inv);
  }
}

// ---------------- launch ----------------
extern "C" void kernel_launch(void* const* d_in, const int* in_sizes, int n_in,
                              void* d_out, int out_size, void* d_ws, size_t ws_size,
                              hipStream_t stream) {
  const float* x      = (const float*)d_in[0];
  const int*   cu     = (const int*)d_in[1];
  const float* rope   = (const float*)d_in[2];
  const float* w_qkv  = (const float*)d_in[3];
  const float* b_qkv  = (const float*)d_in[4];
  const float* w_proj = (const float*)d_in[5];
  const float* b_proj = (const float*)d_in[6];
  float* out = (float*)d_out;
  const int ncu = in_sizes[1];

  char* ws = (char*)d_ws;
  unsigned short* xb     = (unsigned short*)(ws + 0);          // 10485760 B
  unsigned short* wqkvb  = (unsigned short*)(ws + 10485760);   // 9830400 B
  unsigned short* wprojb = (unsigned short*)(ws + 20316160);   // 3276800 B
  float*          cosT   = (float*)(ws + 23592960);            // 655360 B
  float*          sinT   = (float*)(ws + 24248320);            // 655360 B
  unsigned short* qkvb   = (unsigned short*)(ws + 24903680);   // 31457280 B
  unsigned short* Qb     = (unsigned short*)(ws + 56360960);   // 10485760 B ([H][S][80])
  unsigned short* Kb     = (unsigned short*)(ws + 68943872);   // 10485760 B
  unsigned short* Vt     = (unsigned short*)(ws + 81526784);   // 10485760 B (tiled)
  unsigned short* ctxb   = (unsigned short*)(ws + 92012544);   // 10485760 B

  // fused pre: 3 converts + rope table in one dispatch (3112960 items)
  fused_pre_kernel<<<12160, 256, 0, stream>>>(x, w_qkv, w_proj, rope,
                                              xb, wqkvb, wprojb, cosT, sinT);

  gemm256_kernel<1><<<240, 512, 0, stream>>>(xb, wqkvb, b_qkv, (void*)qkvb,
                                             4096, 3840, 1280, 15, 16);
  rope_split_kernel<<<dim3(64, 16), 256, 0, stream>>>(qkvb, cosT, sinT, Qb, Kb, Vt);
  attn_kernel<<<1024, 128, 0, stream>>>(Qb, Kb, Vt, cu, ncu, ctxb);
  gemm128_kernel<0><<<320, 256, 0, stream>>>(ctxb, wprojb, b_proj, (void*)out,
                                             4096, 1280, 1280, 10, 32);
}

// Round 19
// 128.641 us; speedup vs baseline: 1.1338x; 1.0006x over previous
//
#include <hip/hip_runtime.h>
#include <hip/hip_bf16.h>
#include <stdint.h>
#include <stddef.h>

#define S_LEN 4096
#define EMB   1280
#define NH    16
#define HDIM  80
#define N3    3840
#define QSCALE 0.11180339887498949f   // 1/sqrt(80)
#define LOG2E  1.4426950408889634f

typedef __attribute__((ext_vector_type(4))) float f32x4;
typedef __attribute__((ext_vector_type(16))) float f32x16;
typedef __attribute__((ext_vector_type(4))) short s16x4;
typedef __attribute__((ext_vector_type(8))) short s16x8;
typedef __attribute__((ext_vector_type(8))) __bf16 bf16x8;

typedef __attribute__((address_space(1))) const unsigned int as1_u32;
typedef __attribute__((address_space(3))) unsigned int as3_u32;

__device__ __forceinline__ unsigned short f2bf(float f) {
  return __builtin_bit_cast(unsigned short, __float2bfloat16(f));
}
__device__ __forceinline__ float bf2f(unsigned short b) {
  union { unsigned int u; float f; } v; v.u = ((unsigned int)b) << 16;
  return v.f;
}

__device__ __forceinline__ f32x4 mfma16(s16x8 a, s16x8 b, f32x4 c) {
  return __builtin_amdgcn_mfma_f32_16x16x32_bf16(
      __builtin_bit_cast(bf16x8, a), __builtin_bit_cast(bf16x8, b), c, 0, 0, 0);
}
__device__ __forceinline__ f32x16 mfma32(s16x8 a, s16x8 b, f32x16 c) {
  return __builtin_amdgcn_mfma_f32_32x32x16_bf16(
      __builtin_bit_cast(bf16x8, a), __builtin_bit_cast(bf16x8, b), c, 0, 0, 0);
}

__device__ __forceinline__ unsigned cvtpk_bf16(float a, float b) {
  unsigned r;
  asm("v_cvt_pk_bf16_f32 %0, %1, %2" : "=v"(r) : "v"(a), "v"(b));
  return r;
}

// raw hardware exp2
__device__ __forceinline__ float fexp2(float x) {
  float r;
  asm("v_exp_f32 %0, %1" : "=v"(r) : "v"(x));
  return r;
}

__device__ __forceinline__ void gload16(const void* g, void* l) {
  __builtin_amdgcn_global_load_lds((as1_u32*)g, (as3_u32*)l, 16, 0, 0);
}

// ------- fused preprocessing: 3x f32->bf16 convert + rope sincos table -------
__global__ __launch_bounds__(256) void fused_pre_kernel(const float* __restrict__ x,
                                                        const float* __restrict__ wq,
                                                        const float* __restrict__ wp,
                                                        const float* __restrict__ rope,
                                                        unsigned short* __restrict__ xb,
                                                        unsigned short* __restrict__ wqb,
                                                        unsigned short* __restrict__ wpb,
                                                        float* __restrict__ cosT,
                                                        float* __restrict__ sinT) {
  int i = blockIdx.x * 256 + threadIdx.x;
  const float* src;
  unsigned short* dst;
  int j;
  if (i < 1310720) { src = x; dst = xb; j = i; }
  else if (i < 2539520) { src = wq; dst = wqb; j = i - 1310720; }
  else if (i < 2949120) { src = wp; dst = wpb; j = i - 2539520; }
  else {
    int j2 = i - 2949120;
    if (j2 < 163840) {
      float v = rope[j2];
      float s, c;
      sincosf(v, &s, &c);
      cosT[j2] = c; sinT[j2] = s;
    }
    return;
  }
  float4 v = ((const float4*)src)[j];
  s16x4 o;
  o[0] = (short)f2bf(v.x); o[1] = (short)f2bf(v.y);
  o[2] = (short)f2bf(v.z); o[3] = (short)f2bf(v.w);
  ((s16x4*)dst)[j] = o;
}

// ---------------- 256x256 bf16 GEMM, BK=64, deep pipeline (QKV) ----------------
template<int BF16OUT>
__global__ __launch_bounds__(512, 2) void gemm256_kernel(const unsigned short* __restrict__ A,
                                                         const unsigned short* __restrict__ B,
                                                         const float* __restrict__ bias,
                                                         void* __restrict__ Cv,
                                                         int M, int N, int K,
                                                         int gx, int gy) {
  __shared__ __attribute__((aligned(16))) unsigned short lA[2][256 * 64];
  __shared__ __attribute__((aligned(16))) unsigned short lB[2][256 * 64];
  const int t = threadIdx.x;
  const int lane = t & 63, g = lane >> 4, c = lane & 15, cx = c & 7;
  const int w = t >> 6, wm = w >> 2, wn = w & 3;

  int nwg = gx * gy;
  int bid = blockIdx.x;
  int cpx = nwg >> 3;
  int swz = (bid & 7) * cpx + (bid >> 3);
  const int m0 = (swz / gx) * 256, n0 = (swz % gx) * 256;
  const int nt = K >> 6;

  const unsigned short* aS[4];
  const unsigned short* bS[4];
#pragma unroll
  for (int i = 0; i < 4; ++i) {
    int ch = t + i * 512;
    int row = ch >> 3, slot = ch & 7;
    int qsrc = slot ^ (row & 7);
    aS[i] = A + (size_t)(m0 + row) * K + qsrc * 8;
    bS[i] = B + (size_t)(n0 + row) * K + qsrc * 8;
  }

#define STAGE(buf, kt)                                      \
  do {                                                      \
    int _ko = (kt) * 64;                                    \
    gload16(aS[0] + _ko, &lA[buf][(t) * 8]);                \
    gload16(aS[1] + _ko, &lA[buf][(t + 512) * 8]);          \
    gload16(aS[2] + _ko, &lA[buf][(t + 1024) * 8]);         \
    gload16(aS[3] + _ko, &lA[buf][(t + 1536) * 8]);         \
    gload16(bS[0] + _ko, &lB[buf][(t) * 8]);                \
    gload16(bS[1] + _ko, &lB[buf][(t + 512) * 8]);          \
    gload16(bS[2] + _ko, &lB[buf][(t + 1024) * 8]);         \
    gload16(bS[3] + _ko, &lB[buf][(t + 1536) * 8]);         \
  } while (0)

  const f32x4 fz = {0.f, 0.f, 0.f, 0.f};
  f32x4 acc[8][4];
#pragma unroll
  for (int i = 0; i < 8; ++i)
#pragma unroll
    for (int j = 0; j < 4; ++j) acc[i][j] = fz;

  STAGE(0, 0);
  STAGE(1, 1);

  for (int k = 0; k < nt; ++k) {
    const int b = k & 1;
    if (k + 1 < nt) {
      asm volatile("s_waitcnt vmcnt(16)" ::: "memory");
    } else {
      asm volatile("s_waitcnt vmcnt(0)" ::: "memory");
    }
    __builtin_amdgcn_s_barrier();  // B1: buf b fully staged

    s16x8 af0[8], af1[8], bf0[4], bf1[4];
#pragma unroll
    for (int mf = 0; mf < 8; ++mf) {
      const unsigned short* rp = &lA[b][(wm * 128 + mf * 16 + c) * 64];
      af0[mf] = *(const s16x8*)(rp + (g ^ cx) * 8);
      af1[mf] = *(const s16x8*)(rp + ((4 ^ g ^ cx) * 8));
    }
#pragma unroll
    for (int nf = 0; nf < 4; ++nf) {
      const unsigned short* rp = &lB[b][(wn * 64 + nf * 16 + c) * 64];
      bf0[nf] = *(const s16x8*)(rp + (g ^ cx) * 8);
      bf1[nf] = *(const s16x8*)(rp + ((4 ^ g ^ cx) * 8));
    }

    __builtin_amdgcn_s_setprio(1);
#pragma unroll
    for (int mf = 0; mf < 8; ++mf)
#pragma unroll
      for (int nf = 0; nf < 4; ++nf)
        acc[mf][nf] = mfma16(af0[mf], bf0[nf], acc[mf][nf]);
    __builtin_amdgcn_s_setprio(0);

    asm volatile("s_waitcnt lgkmcnt(0)" ::: "memory");
    __builtin_amdgcn_sched_barrier(0);
    __builtin_amdgcn_s_barrier();  // B2: all waves done reading buf b

    if (k + 2 < nt) STAGE(b, k + 2);
    __builtin_amdgcn_sched_barrier(0);

    __builtin_amdgcn_s_setprio(1);
#pragma unroll
    for (int mf = 0; mf < 8; ++mf)
#pragma unroll
      for (int nf = 0; nf < 4; ++nf)
        acc[mf][nf] = mfma16(af1[mf], bf1[nf], acc[mf][nf]);
    __builtin_amdgcn_s_setprio(0);
  }
#undef STAGE

  const int ccol = n0 + wn * 64 + c;
  float bv[4];
#pragma unroll
  for (int nf = 0; nf < 4; ++nf) bv[nf] = bias[ccol + nf * 16];
#pragma unroll
  for (int mf = 0; mf < 8; ++mf)
#pragma unroll
    for (int r = 0; r < 4; ++r) {
      size_t rowoff = (size_t)(m0 + wm * 128 + mf * 16 + g * 4 + r) * N;
#pragma unroll
      for (int nf = 0; nf < 4; ++nf) {
        float vo = acc[mf][nf][r] + bv[nf];
        if (BF16OUT)
          ((unsigned short*)Cv)[rowoff + ccol + nf * 16] = f2bf(vo);
        else
          ((float*)Cv)[rowoff + ccol + nf * 16] = vo;
      }
    }
}

// -------- 128x128 bf16 GEMM, BK=64 deep pipeline (proj) ----
template<int BF16OUT>
__global__ __launch_bounds__(256, 2) void gemm128_kernel(const unsigned short* __restrict__ A,
                                                         const unsigned short* __restrict__ B,
                                                         const float* __restrict__ bias,
                                                         void* __restrict__ Cv,
                                                         int M, int N, int K,
                                                         int gx, int gy) {
  __shared__ __attribute__((aligned(16))) unsigned short lA[2][128 * 64];
  __shared__ __attribute__((aligned(16))) unsigned short lB[2][128 * 64];
  const int t = threadIdx.x;
  const int lane = t & 63, g = lane >> 4, c = lane & 15, cx = c & 7;
  const int w = t >> 6, wm = w >> 1, wn = w & 1;

  int nwg = gx * gy;
  int bid = blockIdx.x;
  int cpx = nwg >> 3;
  int swz = (bid & 7) * cpx + (bid >> 3);
  const int m0 = (swz / gx) * 128, n0 = (swz % gx) * 128;
  const int nt = K >> 6;

  const unsigned short* aS[4];
  const unsigned short* bS[4];
#pragma unroll
  for (int i = 0; i < 4; ++i) {
    int ch = t + i * 256;
    int row = ch >> 3, slot = ch & 7;
    int qsrc = slot ^ (row & 7);
    aS[i] = A + (size_t)(m0 + row) * K + qsrc * 8;
    bS[i] = B + (size_t)(n0 + row) * K + qsrc * 8;
  }

#define STAGE(buf, kt)                                      \
  do {                                                      \
    int _ko = (kt) * 64;                                    \
    gload16(aS[0] + _ko, &lA[buf][(t) * 8]);                \
    gload16(aS[1] + _ko, &lA[buf][(t + 256) * 8]);          \
    gload16(aS[2] + _ko, &lA[buf][(t + 512) * 8]);          \
    gload16(aS[3] + _ko, &lA[buf][(t + 768) * 8]);          \
    gload16(bS[0] + _ko, &lB[buf][(t) * 8]);                \
    gload16(bS[1] + _ko, &lB[buf][(t + 256) * 8]);          \
    gload16(bS[2] + _ko, &lB[buf][(t + 512) * 8]);          \
    gload16(bS[3] + _ko, &lB[buf][(t + 768) * 8]);          \
  } while (0)

  const f32x4 fz = {0.f, 0.f, 0.f, 0.f};
  f32x4 acc[4][4];
#pragma unroll
  for (int i = 0; i < 4; ++i)
#pragma unroll
    for (int j = 0; j < 4; ++j) acc[i][j] = fz;

  STAGE(0, 0);
  STAGE(1, 1);

  for (int k = 0; k < nt; ++k) {
    const int b = k & 1;
    if (k + 1 < nt) {
      asm volatile("s_waitcnt vmcnt(16)" ::: "memory");
    } else {
      asm volatile("s_waitcnt vmcnt(0)" ::: "memory");
    }
    __builtin_amdgcn_s_barrier();

    s16x8 af0[4], af1[4], bf0[4], bf1[4];
#pragma unroll
    for (int mf = 0; mf < 4; ++mf) {
      const unsigned short* rp = &lA[b][(wm * 64 + mf * 16 + c) * 64];
      af0[mf] = *(const s16x8*)(rp + (g ^ cx) * 8);
      af1[mf] = *(const s16x8*)(rp + ((4 ^ g ^ cx) * 8));
    }
#pragma unroll
    for (int nf = 0; nf < 4; ++nf) {
      const unsigned short* rp = &lB[b][(wn * 64 + nf * 16 + c) * 64];
      bf0[nf] = *(const s16x8*)(rp + (g ^ cx) * 8);
      bf1[nf] = *(const s16x8*)(rp + ((4 ^ g ^ cx) * 8));
    }

    __builtin_amdgcn_s_setprio(1);
#pragma unroll
    for (int mf = 0; mf < 4; ++mf)
#pragma unroll
      for (int nf = 0; nf < 4; ++nf)
        acc[mf][nf] = mfma16(af0[mf], bf0[nf], acc[mf][nf]);
    __builtin_amdgcn_s_setprio(0);

    asm volatile("s_waitcnt lgkmcnt(0)" ::: "memory");
    __builtin_amdgcn_sched_barrier(0);
    __builtin_amdgcn_s_barrier();

    if (k + 2 < nt) STAGE(b, k + 2);
    __builtin_amdgcn_sched_barrier(0);

    __builtin_amdgcn_s_setprio(1);
#pragma unroll
    for (int mf = 0; mf < 4; ++mf)
#pragma unroll
      for (int nf = 0; nf < 4; ++nf)
        acc[mf][nf] = mfma16(af1[mf], bf1[nf], acc[mf][nf]);
    __builtin_amdgcn_s_setprio(0);
  }
#undef STAGE

  const int ccol = n0 + wn * 64 + c;
  float bv[4];
#pragma unroll
  for (int nf = 0; nf < 4; ++nf) bv[nf] = bias[ccol + nf * 16];
#pragma unroll
  for (int mf = 0; mf < 4; ++mf)
#pragma unroll
    for (int r = 0; r < 4; ++r) {
      size_t rowoff = (size_t)(m0 + wm * 64 + mf * 16 + g * 4 + r) * N;
#pragma unroll
      for (int nf = 0; nf < 4; ++nf) {
        float vo = acc[mf][nf][r] + bv[nf];
        if (BF16OUT)
          ((unsigned short*)Cv)[rowoff + ccol + nf * 16] = f2bf(vo);
        else
          ((float*)Cv)[rowoff + ccol + nf * 16] = vo;
      }
    }
}

// ---------------- RoPE + QKV split + V transpose (s16x8 vectorized) ----------------
__global__ __launch_bounds__(256) void rope_split_kernel(const unsigned short* __restrict__ qkv,
                                                         const float* __restrict__ cosT,
                                                         const float* __restrict__ sinT,
                                                         unsigned short* __restrict__ Qb,
                                                         unsigned short* __restrict__ Kb,
                                                         unsigned short* __restrict__ Vt) {
  __shared__ unsigned short vls[80][66];
  const int t = threadIdx.x;
  const int s0 = blockIdx.x * 64, h = blockIdx.y;

  // Part A: rope on q and k. items = 64 rows * 5 j8 * 2(q/k), 8 elems each.
  for (int it = t; it < 64 * 5 * 2; it += 256) {
    int qk = it & 1;
    int j8 = (it >> 1) % 5;
    int row = (it >> 1) / 5;
    int s = s0 + row;
    const unsigned short* src = qkv + (size_t)s * N3 + h * 240 + qk * 80;
    unsigned short* dst = (qk ? Kb : Qb) + ((size_t)h * S_LEN + s) * HDIM;
    int d0 = j8 * 8;
    s16x8 a = *(const s16x8*)(src + d0);
    s16x8 b = *(const s16x8*)(src + 40 + d0);
    float4 cs0 = *(const float4*)(cosT + s * 40 + d0);
    float4 cs1 = *(const float4*)(cosT + s * 40 + d0 + 4);
    float4 sn0 = *(const float4*)(sinT + s * 40 + d0);
    float4 sn1 = *(const float4*)(sinT + s * 40 + d0 + 4);
    float sc = qk ? 1.f : (QSCALE * LOG2E);
    float ca[8] = {cs0.x, cs0.y, cs0.z, cs0.w, cs1.x, cs1.y, cs1.z, cs1.w};
    float sa[8] = {sn0.x, sn0.y, sn0.z, sn0.w, sn1.x, sn1.y, sn1.z, sn1.w};
    s16x8 o1, o2;
#pragma unroll
    for (int i = 0; i < 8; ++i) {
      float q1 = bf2f((unsigned short)a[i]);
      float q2 = bf2f((unsigned short)b[i]);
      o1[i] = (short)f2bf((q1 * ca[i] - q2 * sa[i]) * sc);
      o2[i] = (short)f2bf((q2 * ca[i] + q1 * sa[i]) * sc);
    }
    *(s16x8*)(dst + d0) = o1;
    *(s16x8*)(dst + 40 + d0) = o2;
  }

  // Part B: V transpose through LDS -> tiled Vt [H][S/64][80][64]
  for (int it = t; it < 640; it += 256) {
    int row = it / 10, c8 = it % 10;
    int s = s0 + row;
    s16x8 v = *(const s16x8*)(qkv + (size_t)s * N3 + h * 240 + 160 + c8 * 8);
#pragma unroll
    for (int i = 0; i < 8; ++i) vls[c8 * 8 + i][row] = (unsigned short)v[i];
  }
  __syncthreads();
  for (int it = t; it < 640; it += 256) {
    int d = it / 8, s8 = it % 8;
    s16x8 v;
#pragma unroll
    for (int i = 0; i < 8; ++i) v[i] = (short)vls[d][s8 * 8 + i];
    *(s16x8*)(Vt + (((size_t)h * 64 + (s0 >> 6)) * 80 + d) * 64 + s8 * 8) = v;
  }
}

// ---------------- flash attention (round-17 exact: 128 threads, QBLK=64) ----------------
__global__ __launch_bounds__(128, 2) void attn_kernel(const unsigned short* __restrict__ Qb,
                                                      const unsigned short* __restrict__ Kb,
                                                      const unsigned short* __restrict__ Vt,
                                                      const int* __restrict__ cu, int ncu,
                                                      unsigned short* __restrict__ ctx) {
  __shared__ __attribute__((aligned(16))) unsigned short Kl[64 * 128];
  __shared__ __attribute__((aligned(16))) unsigned short Vl[80 * 128];
  const int t = threadIdx.x, lane = t & 63, w = t >> 6;
  const int cq = lane & 31, hi = lane >> 5;

  const int bid = blockIdx.x;
  const int r_ = bid & 7, qi = (bid >> 3) & 15, u = bid >> 7;
  const int grp = u * 8 + r_;
  const int h = grp >> 2, qc = grp & 3;
  const int q0 = qc * 1024 + qi * 64;
  const int nseg = ncu - 1;

  int qlo = 0, qhi = 0, ks = 0, ke = 0, wlo = 0, whi = 0, wlo2 = 0;
  const int myq = q0 + w * 32 + cq;
  const int wr0 = q0 + w * 32, wr1 = wr0 + 31;
  for (int i = 0; i < nseg; ++i) {
    int a = cu[i], b = cu[i + 1];
    if (myq >= a && myq < b) { qlo = a; qhi = b; }
    if (wr0 >= a && wr0 < b) { wlo = a; whi = b; }
    if (wr1 >= a && wr1 < b) { wlo2 = a; }
    if (q0 >= a && q0 < b) ks = a;
    if (q0 + 63 >= a && q0 + 63 < b) ke = b;
  }
  const bool uniform = (wlo == wlo2);
  const int k_begin = ks & ~63;

  s16x8 qf[5];
  {
    const unsigned short* qp = Qb + ((size_t)h * S_LEN + q0 + w * 32 + cq) * HDIM + hi * 8;
#pragma unroll
    for (int kk = 0; kk < 5; ++kk) qf[kk] = *(const s16x8*)(qp + kk * 16);
  }

  int kA[5], vA[5], kO[5], vO[5];
#pragma unroll
  for (int i = 0; i < 5; ++i) {
    int ch = t + i * 128;
    int kr = ch / 10, kc = ch % 10;
    kA[i] = kr * 128 + ((kc ^ (kr & 15)) << 3);
    kO[i] = ch * 8;
    int vd = ch >> 3, vk = ch & 7;
    vA[i] = vd * 128 + ((vk ^ (vd & 15)) << 3);
    vO[i] = ch * 8;
  }
  const unsigned short* kcur = Kb + (size_t)h * S_LEN * HDIM + (size_t)k_begin * HDIM;
  const unsigned short* vcur = Vt + ((size_t)h * 64 + (k_begin >> 6)) * 5120;

  s16x8 onesf;
#pragma unroll
  for (int i = 0; i < 8; ++i) onesf[i] = (short)(unsigned short)0x3F80;

  const f32x16 z16 = {0.f,0.f,0.f,0.f,0.f,0.f,0.f,0.f,0.f,0.f,0.f,0.f,0.f,0.f,0.f,0.f};
  f32x16 o0 = z16, o1 = z16, o2 = z16;

  s16x8 kreg[5], vreg[5];
#pragma unroll
  for (int i = 0; i < 5; ++i) {
    kreg[i] = *(const s16x8*)(kcur + kO[i]);
    vreg[i] = *(const s16x8*)(vcur + vO[i]);
  }

  for (int k0 = k_begin; k0 < ke; k0 += 64) {
    __syncthreads();
#pragma unroll
    for (int i = 0; i < 5; ++i) {
      *(s16x8*)&Kl[kA[i]] = kreg[i];
      *(s16x8*)&Vl[vA[i]] = vreg[i];
    }
    if (k0 + 64 < ke) {
      kcur += 5120; vcur += 5120;
#pragma unroll
      for (int i = 0; i < 5; ++i) {
        kreg[i] = *(const s16x8*)(kcur + kO[i]);
        vreg[i] = *(const s16x8*)(vcur + vO[i]);
      }
    }
    __syncthreads();

    f32x16 sc0 = z16, sc1 = z16;
#pragma unroll
    for (int kk = 0; kk < 5; ++kk) {
      const int cb = ((2 * kk + hi) ^ (cq & 15)) << 3;
      s16x8 kf0 = *(const s16x8*)&Kl[cq * 128 + cb];
      s16x8 kf1 = *(const s16x8*)&Kl[(32 + cq) * 128 + cb];
      sc0 = mfma32(kf0, qf[kk], sc0);
      sc1 = mfma32(kf1, qf[kk], sc1);
    }

    if (!(uniform && k0 >= wlo && k0 + 64 <= whi)) {
#pragma unroll
      for (int r = 0; r < 16; ++r) {
        int key0 = k0 + (r & 3) + 8 * (r >> 2) + 4 * hi;
        int key1 = key0 + 32;
        sc0[r] = (key0 >= qlo && key0 < qhi) ? sc0[r] : -3e38f;
        sc1[r] = (key1 >= qlo && key1 < qhi) ? sc1[r] : -3e38f;
      }
    }

    float pv0[16], pv1[16];
#pragma unroll
    for (int r = 0; r < 16; ++r) {
      pv0[r] = fexp2(sc0[r]);
      pv1[r] = fexp2(sc1[r]);
    }

    unsigned pk0[4][2], pk1[4][2];
#pragma unroll
    for (int q8 = 0; q8 < 4; ++q8)
#pragma unroll
      for (int i = 0; i < 2; ++i) {
        pk0[q8][i] = cvtpk_bf16(pv0[4 * q8 + 2 * i], pv0[4 * q8 + 2 * i + 1]);
        pk1[q8][i] = cvtpk_bf16(pv1[4 * q8 + 2 * i], pv1[4 * q8 + 2 * i + 1]);
      }

#pragma unroll
    for (int kk = 0; kk < 4; ++kk) {
      const int e = (kk & 1) * 2;
      unsigned a0, a1, b0, b1;
      if (kk < 2) { a0 = pk0[e][0]; b0 = pk0[e + 1][0]; a1 = pk0[e][1]; b1 = pk0[e + 1][1]; }
      else        { a0 = pk1[e][0]; b0 = pk1[e + 1][0]; a1 = pk1[e][1]; b1 = pk1[e + 1][1]; }
      auto s0 = __builtin_amdgcn_permlane32_swap(a0, b0, false, false);
      auto s1 = __builtin_amdgcn_permlane32_swap(a1, b1, false, false);
      union { unsigned u[4]; s16x8 v; } fr_;
      fr_.u[0] = s0[0]; fr_.u[1] = s1[0]; fr_.u[2] = s0[1]; fr_.u[3] = s1[1];
      const int cb = ((2 * kk + hi) ^ (cq & 15)) << 3;
      s16x8 vf0 = *(const s16x8*)&Vl[cq * 128 + cb];
      s16x8 vf1 = *(const s16x8*)&Vl[(32 + cq) * 128 + cb];
      s16x8 vf2 = (cq < 16) ? *(const s16x8*)&Vl[(64 + cq) * 128 + cb] : onesf;
      o0 = mfma32(fr_.v, vf0, o0);
      o1 = mfma32(fr_.v, vf1, o1);
      o2 = mfma32(fr_.v, vf2, o2);
    }
  }

#pragma unroll
  for (int r = 0; r < 16; ++r) {
    float lsum = __shfl(o2[r], 16 | (lane & 32));
    float inv = (lsum > 0.f) ? 1.f / lsum : 0.f;
    const int crow = (r & 3) + 8 * (r >> 2) + 4 * hi;
    int srow = q0 + w * 32 + crow;
    size_t base = (size_t)srow * EMB + h * HDIM;
    ctx[base + cq] = f2bf(o0[r] * inv);
    ctx[base + 32 + cq] = f2bf(o1[r] * inv);
    if (cq < 16) ctx[base + 64 + cq] = f2bf(o2[r] * inv);
  }
}

// ---------------- launch ----------------
extern "C" void kernel_launch(void* const* d_in, const int* in_sizes, int n_in,
                              void* d_out, int out_size, void* d_ws, size_t ws_size,
                              hipStream_t stream) {
  const float* x      = (const float*)d_in[0];
  const int*   cu     = (const int*)d_in[1];
  const float* rope   = (const float*)d_in[2];
  const float* w_qkv  = (const float*)d_in[3];
  const float* b_qkv  = (const float*)d_in[4];
  const float* w_proj = (const float*)d_in[5];
  const float* b_proj = (const float*)d_in[6];
  float* out = (float*)d_out;
  const int ncu = in_sizes[1];

  char* ws = (char*)d_ws;
  unsigned short* xb     = (unsigned short*)(ws + 0);          // 10485760 B
  unsigned short* wqkvb  = (unsigned short*)(ws + 10485760);   // 9830400 B
  unsigned short* wprojb = (unsigned short*)(ws + 20316160);   // 3276800 B
  float*          cosT   = (float*)(ws + 23592960);            // 655360 B
  float*          sinT   = (float*)(ws + 24248320);            // 655360 B
  unsigned short* qkvb   = (unsigned short*)(ws + 24903680);   // 31457280 B
  unsigned short* Qb     = (unsigned short*)(ws + 56360960);   // 10485760 B ([H][S][80])
  unsigned short* Kb     = (unsigned short*)(ws + 68943872);   // 10485760 B
  unsigned short* Vt     = (unsigned short*)(ws + 81526784);   // 10485760 B (tiled)
  unsigned short* ctxb   = (unsigned short*)(ws + 92012544);   // 10485760 B

  fused_pre_kernel<<<12160, 256, 0, stream>>>(x, w_qkv, w_proj, rope,
                                              xb, wqkvb, wprojb, cosT, sinT);

  gemm256_kernel<1><<<240, 512, 0, stream>>>(xb, wqkvb, b_qkv, (void*)qkvb,
                                             4096, 3840, 1280, 15, 16);
  rope_split_kernel<<<dim3(64, 16), 256, 0, stream>>>(qkvb, cosT, sinT, Qb, Kb, Vt);
  attn_kernel<<<1024, 128, 0, stream>>>(Qb, Kb, Vt, cu, ncu, ctxb);
  gemm128_kernel<0><<<320, 256, 0, stream>>>(ctxb, wprojb, b_proj, (void*)out,
                                             4096, 1280, 1280, 10, 32);
}

// Round 20
// 127.976 us; speedup vs baseline: 1.1397x; 1.0052x over previous
//
#include <hip/hip_runtime.h>
#include <hip/hip_bf16.h>
#include <stdint.h>
#include <stddef.h>

#define S_LEN 4096
#define EMB   1280
#define NH    16
#define HDIM  80
#define N3    3840
#define QSCALE 0.11180339887498949f   // 1/sqrt(80)
#define LOG2E  1.4426950408889634f

typedef __attribute__((ext_vector_type(4))) float f32x4;
typedef __attribute__((ext_vector_type(16))) float f32x16;
typedef __attribute__((ext_vector_type(4))) short s16x4;
typedef __attribute__((ext_vector_type(8))) short s16x8;
typedef __attribute__((ext_vector_type(8))) __bf16 bf16x8;

typedef __attribute__((address_space(1))) const unsigned int as1_u32;
typedef __attribute__((address_space(3))) unsigned int as3_u32;

__device__ __forceinline__ unsigned short f2bf(float f) {
  return __builtin_bit_cast(unsigned short, __float2bfloat16(f));
}
__device__ __forceinline__ float bf2f(unsigned short b) {
  union { unsigned int u; float f; } v; v.u = ((unsigned int)b) << 16;
  return v.f;
}

__device__ __forceinline__ f32x4 mfma16(s16x8 a, s16x8 b, f32x4 c) {
  return __builtin_amdgcn_mfma_f32_16x16x32_bf16(
      __builtin_bit_cast(bf16x8, a), __builtin_bit_cast(bf16x8, b), c, 0, 0, 0);
}
__device__ __forceinline__ f32x16 mfma32(s16x8 a, s16x8 b, f32x16 c) {
  return __builtin_amdgcn_mfma_f32_32x32x16_bf16(
      __builtin_bit_cast(bf16x8, a), __builtin_bit_cast(bf16x8, b), c, 0, 0, 0);
}

__device__ __forceinline__ unsigned cvtpk_bf16(float a, float b) {
  unsigned r;
  asm("v_cvt_pk_bf16_f32 %0, %1, %2" : "=v"(r) : "v"(a), "v"(b));
  return r;
}

// raw hardware exp2
__device__ __forceinline__ float fexp2(float x) {
  float r;
  asm("v_exp_f32 %0, %1" : "=v"(r) : "v"(x));
  return r;
}

__device__ __forceinline__ void gload16(const void* g, void* l) {
  __builtin_amdgcn_global_load_lds((as1_u32*)g, (as3_u32*)l, 16, 0, 0);
}

// ------- fused preprocessing: 3x f32->bf16 convert + rope sincos table -------
__global__ __launch_bounds__(256) void fused_pre_kernel(const float* __restrict__ x,
                                                        const float* __restrict__ wq,
                                                        const float* __restrict__ wp,
                                                        const float* __restrict__ rope,
                                                        unsigned short* __restrict__ xb,
                                                        unsigned short* __restrict__ wqb,
                                                        unsigned short* __restrict__ wpb,
                                                        float* __restrict__ cosT,
                                                        float* __restrict__ sinT) {
  int i = blockIdx.x * 256 + threadIdx.x;
  const float* src;
  unsigned short* dst;
  int j;
  if (i < 1310720) { src = x; dst = xb; j = i; }
  else if (i < 2539520) { src = wq; dst = wqb; j = i - 1310720; }
  else if (i < 2949120) { src = wp; dst = wpb; j = i - 2539520; }
  else {
    int j2 = i - 2949120;
    if (j2 < 163840) {
      float v = rope[j2];
      float s, c;
      sincosf(v, &s, &c);
      cosT[j2] = c; sinT[j2] = s;
    }
    return;
  }
  float4 v = ((const float4*)src)[j];
  s16x4 o;
  o[0] = (short)f2bf(v.x); o[1] = (short)f2bf(v.y);
  o[2] = (short)f2bf(v.z); o[3] = (short)f2bf(v.w);
  ((s16x4*)dst)[j] = o;
}

// ---------------- 256x256 bf16 GEMM, BK=64, deep pipeline (QKV) ----------------
template<int BF16OUT>
__global__ __launch_bounds__(512, 2) void gemm256_kernel(const unsigned short* __restrict__ A,
                                                         const unsigned short* __restrict__ B,
                                                         const float* __restrict__ bias,
                                                         void* __restrict__ Cv,
                                                         int M, int N, int K,
                                                         int gx, int gy) {
  __shared__ __attribute__((aligned(16))) unsigned short lA[2][256 * 64];
  __shared__ __attribute__((aligned(16))) unsigned short lB[2][256 * 64];
  const int t = threadIdx.x;
  const int lane = t & 63, g = lane >> 4, c = lane & 15, cx = c & 7;
  const int w = t >> 6, wm = w >> 2, wn = w & 3;

  int nwg = gx * gy;
  int bid = blockIdx.x;
  int cpx = nwg >> 3;
  int swz = (bid & 7) * cpx + (bid >> 3);
  const int m0 = (swz / gx) * 256, n0 = (swz % gx) * 256;
  const int nt = K >> 6;

  const unsigned short* aS[4];
  const unsigned short* bS[4];
#pragma unroll
  for (int i = 0; i < 4; ++i) {
    int ch = t + i * 512;
    int row = ch >> 3, slot = ch & 7;
    int qsrc = slot ^ (row & 7);
    aS[i] = A + (size_t)(m0 + row) * K + qsrc * 8;
    bS[i] = B + (size_t)(n0 + row) * K + qsrc * 8;
  }

#define STAGE(buf, kt)                                      \
  do {                                                      \
    int _ko = (kt) * 64;                                    \
    gload16(aS[0] + _ko, &lA[buf][(t) * 8]);                \
    gload16(aS[1] + _ko, &lA[buf][(t + 512) * 8]);          \
    gload16(aS[2] + _ko, &lA[buf][(t + 1024) * 8]);         \
    gload16(aS[3] + _ko, &lA[buf][(t + 1536) * 8]);         \
    gload16(bS[0] + _ko, &lB[buf][(t) * 8]);                \
    gload16(bS[1] + _ko, &lB[buf][(t + 512) * 8]);          \
    gload16(bS[2] + _ko, &lB[buf][(t + 1024) * 8]);         \
    gload16(bS[3] + _ko, &lB[buf][(t + 1536) * 8]);         \
  } while (0)

  const f32x4 fz = {0.f, 0.f, 0.f, 0.f};
  f32x4 acc[8][4];
#pragma unroll
  for (int i = 0; i < 8; ++i)
#pragma unroll
    for (int j = 0; j < 4; ++j) acc[i][j] = fz;

  STAGE(0, 0);
  STAGE(1, 1);

  for (int k = 0; k < nt; ++k) {
    const int b = k & 1;
    if (k + 1 < nt) {
      asm volatile("s_waitcnt vmcnt(16)" ::: "memory");
    } else {
      asm volatile("s_waitcnt vmcnt(0)" ::: "memory");
    }
    __builtin_amdgcn_s_barrier();  // B1: buf b fully staged

    s16x8 af0[8], af1[8], bf0[4], bf1[4];
#pragma unroll
    for (int mf = 0; mf < 8; ++mf) {
      const unsigned short* rp = &lA[b][(wm * 128 + mf * 16 + c) * 64];
      af0[mf] = *(const s16x8*)(rp + (g ^ cx) * 8);
      af1[mf] = *(const s16x8*)(rp + ((4 ^ g ^ cx) * 8));
    }
#pragma unroll
    for (int nf = 0; nf < 4; ++nf) {
      const unsigned short* rp = &lB[b][(wn * 64 + nf * 16 + c) * 64];
      bf0[nf] = *(const s16x8*)(rp + (g ^ cx) * 8);
      bf1[nf] = *(const s16x8*)(rp + ((4 ^ g ^ cx) * 8));
    }

    __builtin_amdgcn_s_setprio(1);
#pragma unroll
    for (int mf = 0; mf < 8; ++mf)
#pragma unroll
      for (int nf = 0; nf < 4; ++nf)
        acc[mf][nf] = mfma16(af0[mf], bf0[nf], acc[mf][nf]);
    __builtin_amdgcn_s_setprio(0);

    asm volatile("s_waitcnt lgkmcnt(0)" ::: "memory");
    __builtin_amdgcn_sched_barrier(0);
    __builtin_amdgcn_s_barrier();  // B2: all waves done reading buf b

    if (k + 2 < nt) STAGE(b, k + 2);
    __builtin_amdgcn_sched_barrier(0);

    __builtin_amdgcn_s_setprio(1);
#pragma unroll
    for (int mf = 0; mf < 8; ++mf)
#pragma unroll
      for (int nf = 0; nf < 4; ++nf)
        acc[mf][nf] = mfma16(af1[mf], bf1[nf], acc[mf][nf]);
    __builtin_amdgcn_s_setprio(0);
  }
#undef STAGE

  const int ccol = n0 + wn * 64 + c;
  float bv[4];
#pragma unroll
  for (int nf = 0; nf < 4; ++nf) bv[nf] = bias[ccol + nf * 16];
#pragma unroll
  for (int mf = 0; mf < 8; ++mf)
#pragma unroll
    for (int r = 0; r < 4; ++r) {
      size_t rowoff = (size_t)(m0 + wm * 128 + mf * 16 + g * 4 + r) * N;
#pragma unroll
      for (int nf = 0; nf < 4; ++nf) {
        float vo = acc[mf][nf][r] + bv[nf];
        if (BF16OUT)
          ((unsigned short*)Cv)[rowoff + ccol + nf * 16] = f2bf(vo);
        else
          ((float*)Cv)[rowoff + ccol + nf * 16] = vo;
      }
    }
}

// -------- 128x128 bf16 GEMM, BK=64 deep pipeline (proj) ----
template<int BF16OUT>
__global__ __launch_bounds__(256, 2) void gemm128_kernel(const unsigned short* __restrict__ A,
                                                         const unsigned short* __restrict__ B,
                                                         const float* __restrict__ bias,
                                                         void* __restrict__ Cv,
                                                         int M, int N, int K,
                                                         int gx, int gy) {
  __shared__ __attribute__((aligned(16))) unsigned short lA[2][128 * 64];
  __shared__ __attribute__((aligned(16))) unsigned short lB[2][128 * 64];
  const int t = threadIdx.x;
  const int lane = t & 63, g = lane >> 4, c = lane & 15, cx = c & 7;
  const int w = t >> 6, wm = w >> 1, wn = w & 1;

  int nwg = gx * gy;
  int bid = blockIdx.x;
  int cpx = nwg >> 3;
  int swz = (bid & 7) * cpx + (bid >> 3);
  const int m0 = (swz / gx) * 128, n0 = (swz % gx) * 128;
  const int nt = K >> 6;

  const unsigned short* aS[4];
  const unsigned short* bS[4];
#pragma unroll
  for (int i = 0; i < 4; ++i) {
    int ch = t + i * 256;
    int row = ch >> 3, slot = ch & 7;
    int qsrc = slot ^ (row & 7);
    aS[i] = A + (size_t)(m0 + row) * K + qsrc * 8;
    bS[i] = B + (size_t)(n0 + row) * K + qsrc * 8;
  }

#define STAGE(buf, kt)                                      \
  do {                                                      \
    int _ko = (kt) * 64;                                    \
    gload16(aS[0] + _ko, &lA[buf][(t) * 8]);                \
    gload16(aS[1] + _ko, &lA[buf][(t + 256) * 8]);          \
    gload16(aS[2] + _ko, &lA[buf][(t + 512) * 8]);          \
    gload16(aS[3] + _ko, &lA[buf][(t + 768) * 8]);          \
    gload16(bS[0] + _ko, &lB[buf][(t) * 8]);                \
    gload16(bS[1] + _ko, &lB[buf][(t + 256) * 8]);          \
    gload16(bS[2] + _ko, &lB[buf][(t + 512) * 8]);          \
    gload16(bS[3] + _ko, &lB[buf][(t + 768) * 8]);          \
  } while (0)

  const f32x4 fz = {0.f, 0.f, 0.f, 0.f};
  f32x4 acc[4][4];
#pragma unroll
  for (int i = 0; i < 4; ++i)
#pragma unroll
    for (int j = 0; j < 4; ++j) acc[i][j] = fz;

  STAGE(0, 0);
  STAGE(1, 1);

  for (int k = 0; k < nt; ++k) {
    const int b = k & 1;
    if (k + 1 < nt) {
      asm volatile("s_waitcnt vmcnt(16)" ::: "memory");
    } else {
      asm volatile("s_waitcnt vmcnt(0)" ::: "memory");
    }
    __builtin_amdgcn_s_barrier();

    s16x8 af0[4], af1[4], bf0[4], bf1[4];
#pragma unroll
    for (int mf = 0; mf < 4; ++mf) {
      const unsigned short* rp = &lA[b][(wm * 64 + mf * 16 + c) * 64];
      af0[mf] = *(const s16x8*)(rp + (g ^ cx) * 8);
      af1[mf] = *(const s16x8*)(rp + ((4 ^ g ^ cx) * 8));
    }
#pragma unroll
    for (int nf = 0; nf < 4; ++nf) {
      const unsigned short* rp = &lB[b][(wn * 64 + nf * 16 + c) * 64];
      bf0[nf] = *(const s16x8*)(rp + (g ^ cx) * 8);
      bf1[nf] = *(const s16x8*)(rp + ((4 ^ g ^ cx) * 8));
    }

    __builtin_amdgcn_s_setprio(1);
#pragma unroll
    for (int mf = 0; mf < 4; ++mf)
#pragma unroll
      for (int nf = 0; nf < 4; ++nf)
        acc[mf][nf] = mfma16(af0[mf], bf0[nf], acc[mf][nf]);
    __builtin_amdgcn_s_setprio(0);

    asm volatile("s_waitcnt lgkmcnt(0)" ::: "memory");
    __builtin_amdgcn_sched_barrier(0);
    __builtin_amdgcn_s_barrier();

    if (k + 2 < nt) STAGE(b, k + 2);
    __builtin_amdgcn_sched_barrier(0);

    __builtin_amdgcn_s_setprio(1);
#pragma unroll
    for (int mf = 0; mf < 4; ++mf)
#pragma unroll
      for (int nf = 0; nf < 4; ++nf)
        acc[mf][nf] = mfma16(af1[mf], bf1[nf], acc[mf][nf]);
    __builtin_amdgcn_s_setprio(0);
  }
#undef STAGE

  const int ccol = n0 + wn * 64 + c;
  float bv[4];
#pragma unroll
  for (int nf = 0; nf < 4; ++nf) bv[nf] = bias[ccol + nf * 16];
#pragma unroll
  for (int mf = 0; mf < 4; ++mf)
#pragma unroll
    for (int r = 0; r < 4; ++r) {
      size_t rowoff = (size_t)(m0 + wm * 64 + mf * 16 + g * 4 + r) * N;
#pragma unroll
      for (int nf = 0; nf < 4; ++nf) {
        float vo = acc[mf][nf][r] + bv[nf];
        if (BF16OUT)
          ((unsigned short*)Cv)[rowoff + ccol + nf * 16] = f2bf(vo);
        else
          ((float*)Cv)[rowoff + ccol + nf * 16] = vo;
      }
    }
}

// ---------------- RoPE + QKV split + V transpose (s16x8 vectorized) ----------------
__global__ __launch_bounds__(256) void rope_split_kernel(const unsigned short* __restrict__ qkv,
                                                         const float* __restrict__ cosT,
                                                         const float* __restrict__ sinT,
                                                         unsigned short* __restrict__ Qb,
                                                         unsigned short* __restrict__ Kb,
                                                         unsigned short* __restrict__ Vt) {
  __shared__ unsigned short vls[80][66];
  const int t = threadIdx.x;
  const int s0 = blockIdx.x * 64, h = blockIdx.y;

  for (int it = t; it < 64 * 5 * 2; it += 256) {
    int qk = it & 1;
    int j8 = (it >> 1) % 5;
    int row = (it >> 1) / 5;
    int s = s0 + row;
    const unsigned short* src = qkv + (size_t)s * N3 + h * 240 + qk * 80;
    unsigned short* dst = (qk ? Kb : Qb) + ((size_t)h * S_LEN + s) * HDIM;
    int d0 = j8 * 8;
    s16x8 a = *(const s16x8*)(src + d0);
    s16x8 b = *(const s16x8*)(src + 40 + d0);
    float4 cs0 = *(const float4*)(cosT + s * 40 + d0);
    float4 cs1 = *(const float4*)(cosT + s * 40 + d0 + 4);
    float4 sn0 = *(const float4*)(sinT + s * 40 + d0);
    float4 sn1 = *(const float4*)(sinT + s * 40 + d0 + 4);
    float sc = qk ? 1.f : (QSCALE * LOG2E);
    float ca[8] = {cs0.x, cs0.y, cs0.z, cs0.w, cs1.x, cs1.y, cs1.z, cs1.w};
    float sa[8] = {sn0.x, sn0.y, sn0.z, sn0.w, sn1.x, sn1.y, sn1.z, sn1.w};
    s16x8 o1, o2;
#pragma unroll
    for (int i = 0; i < 8; ++i) {
      float q1 = bf2f((unsigned short)a[i]);
      float q2 = bf2f((unsigned short)b[i]);
      o1[i] = (short)f2bf((q1 * ca[i] - q2 * sa[i]) * sc);
      o2[i] = (short)f2bf((q2 * ca[i] + q1 * sa[i]) * sc);
    }
    *(s16x8*)(dst + d0) = o1;
    *(s16x8*)(dst + 40 + d0) = o2;
  }

  for (int it = t; it < 640; it += 256) {
    int row = it / 10, c8 = it % 10;
    int s = s0 + row;
    s16x8 v = *(const s16x8*)(qkv + (size_t)s * N3 + h * 240 + 160 + c8 * 8);
#pragma unroll
    for (int i = 0; i < 8; ++i) vls[c8 * 8 + i][row] = (unsigned short)v[i];
  }
  __syncthreads();
  for (int it = t; it < 640; it += 256) {
    int d = it / 8, s8 = it % 8;
    s16x8 v;
#pragma unroll
    for (int i = 0; i < 8; ++i) v[i] = (short)vls[d][s8 * 8 + i];
    *(s16x8*)(Vt + (((size_t)h * 64 + (s0 >> 6)) * 80 + d) * 64 + s8 * 8) = v;
  }
}

// ---------------- flash attention (128 threads, QBLK=64) + T5 setprio ----------------
__global__ __launch_bounds__(128, 2) void attn_kernel(const unsigned short* __restrict__ Qb,
                                                      const unsigned short* __restrict__ Kb,
                                                      const unsigned short* __restrict__ Vt,
                                                      const int* __restrict__ cu, int ncu,
                                                      unsigned short* __restrict__ ctx) {
  __shared__ __attribute__((aligned(16))) unsigned short Kl[64 * 128];
  __shared__ __attribute__((aligned(16))) unsigned short Vl[80 * 128];
  const int t = threadIdx.x, lane = t & 63, w = t >> 6;
  const int cq = lane & 31, hi = lane >> 5;

  const int bid = blockIdx.x;
  const int r_ = bid & 7, qi = (bid >> 3) & 15, u = bid >> 7;
  const int grp = u * 8 + r_;
  const int h = grp >> 2, qc = grp & 3;
  const int q0 = qc * 1024 + qi * 64;
  const int nseg = ncu - 1;

  int qlo = 0, qhi = 0, ks = 0, ke = 0, wlo = 0, whi = 0, wlo2 = 0;
  const int myq = q0 + w * 32 + cq;
  const int wr0 = q0 + w * 32, wr1 = wr0 + 31;
  for (int i = 0; i < nseg; ++i) {
    int a = cu[i], b = cu[i + 1];
    if (myq >= a && myq < b) { qlo = a; qhi = b; }
    if (wr0 >= a && wr0 < b) { wlo = a; whi = b; }
    if (wr1 >= a && wr1 < b) { wlo2 = a; }
    if (q0 >= a && q0 < b) ks = a;
    if (q0 + 63 >= a && q0 + 63 < b) ke = b;
  }
  const bool uniform = (wlo == wlo2);
  const int k_begin = ks & ~63;

  s16x8 qf[5];
  {
    const unsigned short* qp = Qb + ((size_t)h * S_LEN + q0 + w * 32 + cq) * HDIM + hi * 8;
#pragma unroll
    for (int kk = 0; kk < 5; ++kk) qf[kk] = *(const s16x8*)(qp + kk * 16);
  }

  int kA[5], vA[5], kO[5], vO[5];
#pragma unroll
  for (int i = 0; i < 5; ++i) {
    int ch = t + i * 128;
    int kr = ch / 10, kc = ch % 10;
    kA[i] = kr * 128 + ((kc ^ (kr & 15)) << 3);
    kO[i] = ch * 8;
    int vd = ch >> 3, vk = ch & 7;
    vA[i] = vd * 128 + ((vk ^ (vd & 15)) << 3);
    vO[i] = ch * 8;
  }
  const unsigned short* kcur = Kb + (size_t)h * S_LEN * HDIM + (size_t)k_begin * HDIM;
  const unsigned short* vcur = Vt + ((size_t)h * 64 + (k_begin >> 6)) * 5120;

  s16x8 onesf;
#pragma unroll
  for (int i = 0; i < 8; ++i) onesf[i] = (short)(unsigned short)0x3F80;

  const f32x16 z16 = {0.f,0.f,0.f,0.f,0.f,0.f,0.f,0.f,0.f,0.f,0.f,0.f,0.f,0.f,0.f,0.f};
  f32x16 o0 = z16, o1 = z16, o2 = z16;

  s16x8 kreg[5], vreg[5];
#pragma unroll
  for (int i = 0; i < 5; ++i) {
    kreg[i] = *(const s16x8*)(kcur + kO[i]);
    vreg[i] = *(const s16x8*)(vcur + vO[i]);
  }

  for (int k0 = k_begin; k0 < ke; k0 += 64) {
    __syncthreads();
#pragma unroll
    for (int i = 0; i < 5; ++i) {
      *(s16x8*)&Kl[kA[i]] = kreg[i];
      *(s16x8*)&Vl[vA[i]] = vreg[i];
    }
    if (k0 + 64 < ke) {
      kcur += 5120; vcur += 5120;
#pragma unroll
      for (int i = 0; i < 5; ++i) {
        kreg[i] = *(const s16x8*)(kcur + kO[i]);
        vreg[i] = *(const s16x8*)(vcur + vO[i]);
      }
    }
    __syncthreads();

    f32x16 sc0 = z16, sc1 = z16;
    __builtin_amdgcn_s_setprio(1);
#pragma unroll
    for (int kk = 0; kk < 5; ++kk) {
      const int cb = ((2 * kk + hi) ^ (cq & 15)) << 3;
      s16x8 kf0 = *(const s16x8*)&Kl[cq * 128 + cb];
      s16x8 kf1 = *(const s16x8*)&Kl[(32 + cq) * 128 + cb];
      sc0 = mfma32(kf0, qf[kk], sc0);
      sc1 = mfma32(kf1, qf[kk], sc1);
    }
    __builtin_amdgcn_s_setprio(0);

    if (!(uniform && k0 >= wlo && k0 + 64 <= whi)) {
#pragma unroll
      for (int r = 0; r < 16; ++r) {
        int key0 = k0 + (r & 3) + 8 * (r >> 2) + 4 * hi;
        int key1 = key0 + 32;
        sc0[r] = (key0 >= qlo && key0 < qhi) ? sc0[r] : -3e38f;
        sc1[r] = (key1 >= qlo && key1 < qhi) ? sc1[r] : -3e38f;
      }
    }

    float pv0[16], pv1[16];
#pragma unroll
    for (int r = 0; r < 16; ++r) {
      pv0[r] = fexp2(sc0[r]);
      pv1[r] = fexp2(sc1[r]);
    }

    unsigned pk0[4][2], pk1[4][2];
#pragma unroll
    for (int q8 = 0; q8 < 4; ++q8)
#pragma unroll
      for (int i = 0; i < 2; ++i) {
        pk0[q8][i] = cvtpk_bf16(pv0[4 * q8 + 2 * i], pv0[4 * q8 + 2 * i + 1]);
        pk1[q8][i] = cvtpk_bf16(pv1[4 * q8 + 2 * i], pv1[4 * q8 + 2 * i + 1]);
      }

    __builtin_amdgcn_s_setprio(1);
#pragma unroll
    for (int kk = 0; kk < 4; ++kk) {
      const int e = (kk & 1) * 2;
      unsigned a0, a1, b0, b1;
      if (kk < 2) { a0 = pk0[e][0]; b0 = pk0[e + 1][0]; a1 = pk0[e][1]; b1 = pk0[e + 1][1]; }
      else        { a0 = pk1[e][0]; b0 = pk1[e + 1][0]; a1 = pk1[e][1]; b1 = pk1[e + 1][1]; }
      auto s0 = __builtin_amdgcn_permlane32_swap(a0, b0, false, false);
      auto s1 = __builtin_amdgcn_permlane32_swap(a1, b1, false, false);
      union { unsigned u[4]; s16x8 v; } fr_;
      fr_.u[0] = s0[0]; fr_.u[1] = s1[0]; fr_.u[2] = s0[1]; fr_.u[3] = s1[1];
      const int cb = ((2 * kk + hi) ^ (cq & 15)) << 3;
      s16x8 vf0 = *(const s16x8*)&Vl[cq * 128 + cb];
      s16x8 vf1 = *(const s16x8*)&Vl[(32 + cq) * 128 + cb];
      s16x8 vf2 = (cq < 16) ? *(const s16x8*)&Vl[(64 + cq) * 128 + cb] : onesf;
      o0 = mfma32(fr_.v, vf0, o0);
      o1 = mfma32(fr_.v, vf1, o1);
      o2 = mfma32(fr_.v, vf2, o2);
    }
    __builtin_amdgcn_s_setprio(0);
  }

#pragma unroll
  for (int r = 0; r < 16; ++r) {
    float lsum = __shfl(o2[r], 16 | (lane & 32));
    float inv = (lsum > 0.f) ? 1.f / lsum : 0.f;
    const int crow = (r & 3) + 8 * (r >> 2) + 4 * hi;
    int srow = q0 + w * 32 + crow;
    size_t base = (size_t)srow * EMB + h * HDIM;
    ctx[base + cq] = f2bf(o0[r] * inv);
    ctx[base + 32 + cq] = f2bf(o1[r] * inv);
    if (cq < 16) ctx[base + 64 + cq] = f2bf(o2[r] * inv);
  }
}

// ---------------- launch ----------------
extern "C" void kernel_launch(void* const* d_in, const int* in_sizes, int n_in,
                              void* d_out, int out_size, void* d_ws, size_t ws_size,
                              hipStream_t stream) {
  const float* x      = (const float*)d_in[0];
  const int*   cu     = (const int*)d_in[1];
  const float* rope   = (const float*)d_in[2];
  const float* w_qkv  = (const float*)d_in[3];
  const float* b_qkv  = (const float*)d_in[4];
  const float* w_proj = (const float*)d_in[5];
  const float* b_proj = (const float*)d_in[6];
  float* out = (float*)d_out;
  const int ncu = in_sizes[1];

  char* ws = (char*)d_ws;
  unsigned short* xb     = (unsigned short*)(ws + 0);          // 10485760 B
  unsigned short* wqkvb  = (unsigned short*)(ws + 10485760);   // 9830400 B
  unsigned short* wprojb = (unsigned short*)(ws + 20316160);   // 3276800 B
  float*          cosT   = (float*)(ws + 23592960);            // 655360 B
  float*          sinT   = (float*)(ws + 24248320);            // 655360 B
  unsigned short* qkvb   = (unsigned short*)(ws + 24903680);   // 31457280 B
  unsigned short* Qb     = (unsigned short*)(ws + 56360960);   // 10485760 B ([H][S][80])
  unsigned short* Kb     = (unsigned short*)(ws + 68943872);   // 10485760 B
  unsigned short* Vt     = (unsigned short*)(ws + 81526784);   // 10485760 B (tiled)
  unsigned short* ctxb   = (unsigned short*)(ws + 92012544);   // 10485760 B

  fused_pre_kernel<<<12160, 256, 0, stream>>>(x, w_qkv, w_proj, rope,
                                              xb, wqkvb, wprojb, cosT, sinT);

  gemm256_kernel<1><<<240, 512, 0, stream>>>(xb, wqkvb, b_qkv, (void*)qkvb,
                                             4096, 3840, 1280, 15, 16);
  rope_split_kernel<<<dim3(64, 16), 256, 0, stream>>>(qkvb, cosT, sinT, Qb, Kb, Vt);
  attn_kernel<<<1024, 128, 0, stream>>>(Qb, Kb, Vt, cu, ncu, ctxb);
  gemm128_kernel<0><<<320, 256, 0, stream>>>(ctxb, wprojb, b_proj, (void*)out,
                                             4096, 1280, 1280, 10, 32);
}

// Round 21
// 126.502 us; speedup vs baseline: 1.1530x; 1.0117x over previous
//
#include <hip/hip_runtime.h>
#include <hip/hip_bf16.h>
#include <stdint.h>
#include <stddef.h>

#define S_LEN 4096
#define EMB   1280
#define NH    16
#define HDIM  80
#define N3    3840
#define QSCALE 0.11180339887498949f   // 1/sqrt(80)
#define LOG2E  1.4426950408889634f

typedef __attribute__((ext_vector_type(4))) float f32x4;
typedef __attribute__((ext_vector_type(16))) float f32x16;
typedef __attribute__((ext_vector_type(4))) short s16x4;
typedef __attribute__((ext_vector_type(8))) short s16x8;
typedef __attribute__((ext_vector_type(8))) __bf16 bf16x8;

typedef __attribute__((address_space(1))) const unsigned int as1_u32;
typedef __attribute__((address_space(3))) unsigned int as3_u32;

__device__ __forceinline__ unsigned short f2bf(float f) {
  return __builtin_bit_cast(unsigned short, __float2bfloat16(f));
}
__device__ __forceinline__ float bf2f(unsigned short b) {
  union { unsigned int u; float f; } v; v.u = ((unsigned int)b) << 16;
  return v.f;
}

__device__ __forceinline__ f32x4 mfma16(s16x8 a, s16x8 b, f32x4 c) {
  return __builtin_amdgcn_mfma_f32_16x16x32_bf16(
      __builtin_bit_cast(bf16x8, a), __builtin_bit_cast(bf16x8, b), c, 0, 0, 0);
}
__device__ __forceinline__ f32x16 mfma32(s16x8 a, s16x8 b, f32x16 c) {
  return __builtin_amdgcn_mfma_f32_32x32x16_bf16(
      __builtin_bit_cast(bf16x8, a), __builtin_bit_cast(bf16x8, b), c, 0, 0, 0);
}

__device__ __forceinline__ unsigned cvtpk_bf16(float a, float b) {
  unsigned r;
  asm("v_cvt_pk_bf16_f32 %0, %1, %2" : "=v"(r) : "v"(a), "v"(b));
  return r;
}

// raw hardware exp2
__device__ __forceinline__ float fexp2(float x) {
  float r;
  asm("v_exp_f32 %0, %1" : "=v"(r) : "v"(x));
  return r;
}

__device__ __forceinline__ void gload16(const void* g, void* l) {
  __builtin_amdgcn_global_load_lds((as1_u32*)g, (as3_u32*)l, 16, 0, 0);
}

// ------- fused preprocessing: 3x f32->bf16 convert + rope sincos table -------
__global__ __launch_bounds__(256) void fused_pre_kernel(const float* __restrict__ x,
                                                        const float* __restrict__ wq,
                                                        const float* __restrict__ wp,
                                                        const float* __restrict__ rope,
                                                        unsigned short* __restrict__ xb,
                                                        unsigned short* __restrict__ wqb,
                                                        unsigned short* __restrict__ wpb,
                                                        float* __restrict__ cosT,
                                                        float* __restrict__ sinT) {
  int i = blockIdx.x * 256 + threadIdx.x;
  const float* src;
  unsigned short* dst;
  int j;
  if (i < 1310720) { src = x; dst = xb; j = i; }
  else if (i < 2539520) { src = wq; dst = wqb; j = i - 1310720; }
  else if (i < 2949120) { src = wp; dst = wpb; j = i - 2539520; }
  else {
    int j2 = i - 2949120;
    if (j2 < 163840) {
      float v = rope[j2];
      float s, c;
      sincosf(v, &s, &c);
      cosT[j2] = c; sinT[j2] = s;
    }
    return;
  }
  float4 v = ((const float4*)src)[j];
  s16x4 o;
  o[0] = (short)f2bf(v.x); o[1] = (short)f2bf(v.y);
  o[2] = (short)f2bf(v.z); o[3] = (short)f2bf(v.w);
  ((s16x4*)dst)[j] = o;
}

// ------- 256x256 bf16 GEMM, BK=64, 4-phase interleaved pipeline (QKV) -------
// Half-tile ledger (derived, all windows barrier-verified):
//   A stored as 2 halves of 128 rows (wave wm reads only its half);
//   B read wholly in ph0 -> B-halves free after ph0-end barrier.
// Per K-tile k (buf b=k&1), 2 barriers total:
//   vmcnt(4: exactly B(k+1) in flight) ; BARRIER  <- K-tile k landed
//   ph0: read B(8)+A-mf01(4); stage A-h0(k+1); 16 MFMA; lgkm(0); BARRIER
//   ph1: read A-mf23; stage A-h1(k+1); 16 MFMA
//   ph2: read A-mf45; stage B-h0(k+2); 16 MFMA
//   ph3: read A-mf67; stage B-h1(k+2); 16 MFMA
// Prologue stages A(0),B(0),B(1) = 12 loads (oldest-first for vmcnt count).
template<int BF16OUT>
__global__ __launch_bounds__(512, 2) void gemm256_kernel(const unsigned short* __restrict__ A,
                                                         const unsigned short* __restrict__ B,
                                                         const float* __restrict__ bias,
                                                         void* __restrict__ Cv,
                                                         int M, int N, int K,
                                                         int gx, int gy) {
  __shared__ __attribute__((aligned(16))) unsigned short lA[32768]; // [dbuf][half][8192]
  __shared__ __attribute__((aligned(16))) unsigned short lB[32768];
  const int t = threadIdx.x;
  const int lane = t & 63, g = lane >> 4, c = lane & 15;
  const int w = t >> 6, wm = w >> 2, wn = w & 3;

  int nwg = gx * gy;
  int bid = blockIdx.x;
  int cpx = nwg >> 3;
  int swz = (bid & 7) * cpx + (bid >> 3);
  const int m0 = (swz / gx) * 256, n0 = (swz % gx) * 256;
  const int nt = K >> 6;
  const size_t halfstep = 128 * (size_t)K;

  // staging sources: chunk L = t + i*512 within a half-tile (1024 chunks, 128 rows)
  const unsigned short* aS[2];
  const unsigned short* bS[2];
#pragma unroll
  for (int i = 0; i < 2; ++i) {
    int L = t + i * 512;
    int rowH = L >> 3, qsrc = (L & 7) ^ (rowH & 7);
    aS[i] = A + (size_t)(m0 + rowH) * K + qsrc * 8;
    bS[i] = B + (size_t)(n0 + rowH) * K + qsrc * 8;
  }

#define STAGE_A(db, h, kt)                                                        \
  do {                                                                            \
    int _ko = (kt) * 64;                                                          \
    gload16(aS[0] + (size_t)(h) * halfstep + _ko, &lA[((db)*2+(h))*8192 + t*8]);  \
    gload16(aS[1] + (size_t)(h) * halfstep + _ko, &lA[((db)*2+(h))*8192 + (t+512)*8]); \
  } while (0)
#define STAGE_B(db, h, kt)                                                        \
  do {                                                                            \
    int _ko = (kt) * 64;                                                          \
    gload16(bS[0] + (size_t)(h) * halfstep + _ko, &lB[((db)*2+(h))*8192 + t*8]);  \
    gload16(bS[1] + (size_t)(h) * halfstep + _ko, &lB[((db)*2+(h))*8192 + (t+512)*8]); \
  } while (0)

  // read offsets (within half): phys slot for global chunk q of row r is q^(r&7)
  int offA[8][2];
#pragma unroll
  for (int mf = 0; mf < 8; ++mf) {
    int r = mf * 16 + c;
#pragma unroll
    for (int kk = 0; kk < 2; ++kk)
      offA[mf][kk] = r * 64 + (((kk * 4 + g) ^ (r & 7)) * 8);
  }
  int offB[4][2];
#pragma unroll
  for (int nf = 0; nf < 4; ++nf) {
    int rb = (wn & 1) * 64 + nf * 16 + c;
#pragma unroll
    for (int kk = 0; kk < 2; ++kk)
      offB[nf][kk] = rb * 64 + (((kk * 4 + g) ^ (rb & 7)) * 8);
  }

  const f32x4 fz = {0.f, 0.f, 0.f, 0.f};
  f32x4 acc[8][4];
#pragma unroll
  for (int i = 0; i < 8; ++i)
#pragma unroll
    for (int j = 0; j < 4; ++j) acc[i][j] = fz;

  // prologue (issue order matters for vmcnt ledger)
  STAGE_A(0, 0, 0); STAGE_A(0, 1, 0);
  STAGE_B(0, 0, 0); STAGE_B(0, 1, 0);
  STAGE_B(1, 0, 1); STAGE_B(1, 1, 1);

  for (int k = 0; k < nt; ++k) {
    const int b = k & 1;
    if (k + 1 < nt) {
      asm volatile("s_waitcnt vmcnt(4)" ::: "memory");
    } else {
      asm volatile("s_waitcnt vmcnt(0)" ::: "memory");
    }
    __builtin_amdgcn_s_barrier();   // K-tile k fully landed (all waves)

    const unsigned short* abase = &lA[(b * 2 + wm) * 8192];
    const unsigned short* bbase = &lB[(b * 2 + (wn >> 1)) * 8192];

    // ---- ph0: B all + A mf0,1 ; stage A-h0(k+1)
    s16x8 bfr[4][2];
#pragma unroll
    for (int nf = 0; nf < 4; ++nf) {
      bfr[nf][0] = *(const s16x8*)&bbase[offB[nf][0]];
      bfr[nf][1] = *(const s16x8*)&bbase[offB[nf][1]];
    }
    {
      s16x8 a0k0 = *(const s16x8*)&abase[offA[0][0]];
      s16x8 a0k1 = *(const s16x8*)&abase[offA[0][1]];
      s16x8 a1k0 = *(const s16x8*)&abase[offA[1][0]];
      s16x8 a1k1 = *(const s16x8*)&abase[offA[1][1]];
      if (k + 1 < nt) STAGE_A(b ^ 1, 0, k + 1);
      __builtin_amdgcn_s_setprio(1);
#pragma unroll
      for (int nf = 0; nf < 4; ++nf) {
        acc[0][nf] = mfma16(a0k0, bfr[nf][0], acc[0][nf]);
        acc[0][nf] = mfma16(a0k1, bfr[nf][1], acc[0][nf]);
        acc[1][nf] = mfma16(a1k0, bfr[nf][0], acc[1][nf]);
        acc[1][nf] = mfma16(a1k1, bfr[nf][1], acc[1][nf]);
      }
      __builtin_amdgcn_s_setprio(0);
    }
    asm volatile("s_waitcnt lgkmcnt(0)" ::: "memory");
    __builtin_amdgcn_sched_barrier(0);
    __builtin_amdgcn_s_barrier();   // B-halves of buf b free

    // ---- ph1: A mf2,3 ; stage A-h1(k+1)
    {
      s16x8 a0k0 = *(const s16x8*)&abase[offA[2][0]];
      s16x8 a0k1 = *(const s16x8*)&abase[offA[2][1]];
      s16x8 a1k0 = *(const s16x8*)&abase[offA[3][0]];
      s16x8 a1k1 = *(const s16x8*)&abase[offA[3][1]];
      if (k + 1 < nt) STAGE_A(b ^ 1, 1, k + 1);
      __builtin_amdgcn_s_setprio(1);
#pragma unroll
      for (int nf = 0; nf < 4; ++nf) {
        acc[2][nf] = mfma16(a0k0, bfr[nf][0], acc[2][nf]);
        acc[2][nf] = mfma16(a0k1, bfr[nf][1], acc[2][nf]);
        acc[3][nf] = mfma16(a1k0, bfr[nf][0], acc[3][nf]);
        acc[3][nf] = mfma16(a1k1, bfr[nf][1], acc[3][nf]);
      }
      __builtin_amdgcn_s_setprio(0);
    }
    __builtin_amdgcn_sched_barrier(0);

    // ---- ph2: A mf4,5 ; stage B-h0(k+2)
    {
      s16x8 a0k0 = *(const s16x8*)&abase[offA[4][0]];
      s16x8 a0k1 = *(const s16x8*)&abase[offA[4][1]];
      s16x8 a1k0 = *(const s16x8*)&abase[offA[5][0]];
      s16x8 a1k1 = *(const s16x8*)&abase[offA[5][1]];
      if (k + 2 < nt) STAGE_B(b, 0, k + 2);
      __builtin_amdgcn_s_setprio(1);
#pragma unroll
      for (int nf = 0; nf < 4; ++nf) {
        acc[4][nf] = mfma16(a0k0, bfr[nf][0], acc[4][nf]);
        acc[4][nf] = mfma16(a0k1, bfr[nf][1], acc[4][nf]);
        acc[5][nf] = mfma16(a1k0, bfr[nf][0], acc[5][nf]);
        acc[5][nf] = mfma16(a1k1, bfr[nf][1], acc[5][nf]);
      }
      __builtin_amdgcn_s_setprio(0);
    }
    __builtin_amdgcn_sched_barrier(0);

    // ---- ph3: A mf6,7 ; stage B-h1(k+2)
    {
      s16x8 a0k0 = *(const s16x8*)&abase[offA[6][0]];
      s16x8 a0k1 = *(const s16x8*)&abase[offA[6][1]];
      s16x8 a1k0 = *(const s16x8*)&abase[offA[7][0]];
      s16x8 a1k1 = *(const s16x8*)&abase[offA[7][1]];
      if (k + 2 < nt) STAGE_B(b, 1, k + 2);
      __builtin_amdgcn_s_setprio(1);
#pragma unroll
      for (int nf = 0; nf < 4; ++nf) {
        acc[6][nf] = mfma16(a0k0, bfr[nf][0], acc[6][nf]);
        acc[6][nf] = mfma16(a0k1, bfr[nf][1], acc[6][nf]);
        acc[7][nf] = mfma16(a1k0, bfr[nf][0], acc[7][nf]);
        acc[7][nf] = mfma16(a1k1, bfr[nf][1], acc[7][nf]);
      }
      __builtin_amdgcn_s_setprio(0);
    }
  }
#undef STAGE_A
#undef STAGE_B

  const int ccol = n0 + wn * 64 + c;
  float bv[4];
#pragma unroll
  for (int nf = 0; nf < 4; ++nf) bv[nf] = bias[ccol + nf * 16];
#pragma unroll
  for (int mf = 0; mf < 8; ++mf)
#pragma unroll
    for (int r = 0; r < 4; ++r) {
      size_t rowoff = (size_t)(m0 + wm * 128 + mf * 16 + g * 4 + r) * N;
#pragma unroll
      for (int nf = 0; nf < 4; ++nf) {
        float vo = acc[mf][nf][r] + bv[nf];
        if (BF16OUT)
          ((unsigned short*)Cv)[rowoff + ccol + nf * 16] = f2bf(vo);
        else
          ((float*)Cv)[rowoff + ccol + nf * 16] = vo;
      }
    }
}

// -------- 128x128 bf16 GEMM, BK=64 deep pipeline (proj) ----
template<int BF16OUT>
__global__ __launch_bounds__(256, 2) void gemm128_kernel(const unsigned short* __restrict__ A,
                                                         const unsigned short* __restrict__ B,
                                                         const float* __restrict__ bias,
                                                         void* __restrict__ Cv,
                                                         int M, int N, int K,
                                                         int gx, int gy) {
  __shared__ __attribute__((aligned(16))) unsigned short lA[2][128 * 64];
  __shared__ __attribute__((aligned(16))) unsigned short lB[2][128 * 64];
  const int t = threadIdx.x;
  const int lane = t & 63, g = lane >> 4, c = lane & 15, cx = c & 7;
  const int w = t >> 6, wm = w >> 1, wn = w & 1;

  int nwg = gx * gy;
  int bid = blockIdx.x;
  int cpx = nwg >> 3;
  int swz = (bid & 7) * cpx + (bid >> 3);
  const int m0 = (swz / gx) * 128, n0 = (swz % gx) * 128;
  const int nt = K >> 6;

  const unsigned short* aS[4];
  const unsigned short* bS[4];
#pragma unroll
  for (int i = 0; i < 4; ++i) {
    int ch = t + i * 256;
    int row = ch >> 3, slot = ch & 7;
    int qsrc = slot ^ (row & 7);
    aS[i] = A + (size_t)(m0 + row) * K + qsrc * 8;
    bS[i] = B + (size_t)(n0 + row) * K + qsrc * 8;
  }

#define STAGE(buf, kt)                                      \
  do {                                                      \
    int _ko = (kt) * 64;                                    \
    gload16(aS[0] + _ko, &lA[buf][(t) * 8]);                \
    gload16(aS[1] + _ko, &lA[buf][(t + 256) * 8]);          \
    gload16(aS[2] + _ko, &lA[buf][(t + 512) * 8]);          \
    gload16(aS[3] + _ko, &lA[buf][(t + 768) * 8]);          \
    gload16(bS[0] + _ko, &lB[buf][(t) * 8]);                \
    gload16(bS[1] + _ko, &lB[buf][(t + 256) * 8]);          \
    gload16(bS[2] + _ko, &lB[buf][(t + 512) * 8]);          \
    gload16(bS[3] + _ko, &lB[buf][(t + 768) * 8]);          \
  } while (0)

  const f32x4 fz = {0.f, 0.f, 0.f, 0.f};
  f32x4 acc[4][4];
#pragma unroll
  for (int i = 0; i < 4; ++i)
#pragma unroll
    for (int j = 0; j < 4; ++j) acc[i][j] = fz;

  STAGE(0, 0);
  STAGE(1, 1);

  for (int k = 0; k < nt; ++k) {
    const int b = k & 1;
    if (k + 1 < nt) {
      asm volatile("s_waitcnt vmcnt(16)" ::: "memory");
    } else {
      asm volatile("s_waitcnt vmcnt(0)" ::: "memory");
    }
    __builtin_amdgcn_s_barrier();

    s16x8 af0[4], af1[4], bf0[4], bf1[4];
#pragma unroll
    for (int mf = 0; mf < 4; ++mf) {
      const unsigned short* rp = &lA[b][(wm * 64 + mf * 16 + c) * 64];
      af0[mf] = *(const s16x8*)(rp + (g ^ cx) * 8);
      af1[mf] = *(const s16x8*)(rp + ((4 ^ g ^ cx) * 8));
    }
#pragma unroll
    for (int nf = 0; nf < 4; ++nf) {
      const unsigned short* rp = &lB[b][(wn * 64 + nf * 16 + c) * 64];
      bf0[nf] = *(const s16x8*)(rp + (g ^ cx) * 8);
      bf1[nf] = *(const s16x8*)(rp + ((4 ^ g ^ cx) * 8));
    }

    __builtin_amdgcn_s_setprio(1);
#pragma unroll
    for (int mf = 0; mf < 4; ++mf)
#pragma unroll
      for (int nf = 0; nf < 4; ++nf)
        acc[mf][nf] = mfma16(af0[mf], bf0[nf], acc[mf][nf]);
    __builtin_amdgcn_s_setprio(0);

    asm volatile("s_waitcnt lgkmcnt(0)" ::: "memory");
    __builtin_amdgcn_sched_barrier(0);
    __builtin_amdgcn_s_barrier();

    if (k + 2 < nt) STAGE(b, k + 2);
    __builtin_amdgcn_sched_barrier(0);

    __builtin_amdgcn_s_setprio(1);
#pragma unroll
    for (int mf = 0; mf < 4; ++mf)
#pragma unroll
      for (int nf = 0; nf < 4; ++nf)
        acc[mf][nf] = mfma16(af1[mf], bf1[nf], acc[mf][nf]);
    __builtin_amdgcn_s_setprio(0);
  }
#undef STAGE

  const int ccol = n0 + wn * 64 + c;
  float bv[4];
#pragma unroll
  for (int nf = 0; nf < 4; ++nf) bv[nf] = bias[ccol + nf * 16];
#pragma unroll
  for (int mf = 0; mf < 4; ++mf)
#pragma unroll
    for (int r = 0; r < 4; ++r) {
      size_t rowoff = (size_t)(m0 + wm * 64 + mf * 16 + g * 4 + r) * N;
#pragma unroll
      for (int nf = 0; nf < 4; ++nf) {
        float vo = acc[mf][nf][r] + bv[nf];
        if (BF16OUT)
          ((unsigned short*)Cv)[rowoff + ccol + nf * 16] = f2bf(vo);
        else
          ((float*)Cv)[rowoff + ccol + nf * 16] = vo;
      }
    }
}

// ---------------- RoPE + QKV split + V transpose (s16x8 vectorized) ----------------
__global__ __launch_bounds__(256) void rope_split_kernel(const unsigned short* __restrict__ qkv,
                                                         const float* __restrict__ cosT,
                                                         const float* __restrict__ sinT,
                                                         unsigned short* __restrict__ Qb,
                                                         unsigned short* __restrict__ Kb,
                                                         unsigned short* __restrict__ Vt) {
  __shared__ unsigned short vls[80][66];
  const int t = threadIdx.x;
  const int s0 = blockIdx.x * 64, h = blockIdx.y;

  for (int it = t; it < 64 * 5 * 2; it += 256) {
    int qk = it & 1;
    int j8 = (it >> 1) % 5;
    int row = (it >> 1) / 5;
    int s = s0 + row;
    const unsigned short* src = qkv + (size_t)s * N3 + h * 240 + qk * 80;
    unsigned short* dst = (qk ? Kb : Qb) + ((size_t)h * S_LEN + s) * HDIM;
    int d0 = j8 * 8;
    s16x8 a = *(const s16x8*)(src + d0);
    s16x8 b = *(const s16x8*)(src + 40 + d0);
    float4 cs0 = *(const float4*)(cosT + s * 40 + d0);
    float4 cs1 = *(const float4*)(cosT + s * 40 + d0 + 4);
    float4 sn0 = *(const float4*)(sinT + s * 40 + d0);
    float4 sn1 = *(const float4*)(sinT + s * 40 + d0 + 4);
    float sc = qk ? 1.f : (QSCALE * LOG2E);
    float ca[8] = {cs0.x, cs0.y, cs0.z, cs0.w, cs1.x, cs1.y, cs1.z, cs1.w};
    float sa[8] = {sn0.x, sn0.y, sn0.z, sn0.w, sn1.x, sn1.y, sn1.z, sn1.w};
    s16x8 o1, o2;
#pragma unroll
    for (int i = 0; i < 8; ++i) {
      float q1 = bf2f((unsigned short)a[i]);
      float q2 = bf2f((unsigned short)b[i]);
      o1[i] = (short)f2bf((q1 * ca[i] - q2 * sa[i]) * sc);
      o2[i] = (short)f2bf((q2 * ca[i] + q1 * sa[i]) * sc);
    }
    *(s16x8*)(dst + d0) = o1;
    *(s16x8*)(dst + 40 + d0) = o2;
  }

  for (int it = t; it < 640; it += 256) {
    int row = it / 10, c8 = it % 10;
    int s = s0 + row;
    s16x8 v = *(const s16x8*)(qkv + (size_t)s * N3 + h * 240 + 160 + c8 * 8);
#pragma unroll
    for (int i = 0; i < 8; ++i) vls[c8 * 8 + i][row] = (unsigned short)v[i];
  }
  __syncthreads();
  for (int it = t; it < 640; it += 256) {
    int d = it / 8, s8 = it % 8;
    s16x8 v;
#pragma unroll
    for (int i = 0; i < 8; ++i) v[i] = (short)vls[d][s8 * 8 + i];
    *(s16x8*)(Vt + (((size_t)h * 64 + (s0 >> 6)) * 80 + d) * 64 + s8 * 8) = v;
  }
}

// ---------------- flash attention (128 threads, QBLK=64) + T5 setprio ----------------
__global__ __launch_bounds__(128, 2) void attn_kernel(const unsigned short* __restrict__ Qb,
                                                      const unsigned short* __restrict__ Kb,
                                                      const unsigned short* __restrict__ Vt,
                                                      const int* __restrict__ cu, int ncu,
                                                      unsigned short* __restrict__ ctx) {
  __shared__ __attribute__((aligned(16))) unsigned short Kl[64 * 128];
  __shared__ __attribute__((aligned(16))) unsigned short Vl[80 * 128];
  const int t = threadIdx.x, lane = t & 63, w = t >> 6;
  const int cq = lane & 31, hi = lane >> 5;

  const int bid = blockIdx.x;
  const int r_ = bid & 7, qi = (bid >> 3) & 15, u = bid >> 7;
  const int grp = u * 8 + r_;
  const int h = grp >> 2, qc = grp & 3;
  const int q0 = qc * 1024 + qi * 64;
  const int nseg = ncu - 1;

  int qlo = 0, qhi = 0, ks = 0, ke = 0, wlo = 0, whi = 0, wlo2 = 0;
  const int myq = q0 + w * 32 + cq;
  const int wr0 = q0 + w * 32, wr1 = wr0 + 31;
  for (int i = 0; i < nseg; ++i) {
    int a = cu[i], b = cu[i + 1];
    if (myq >= a && myq < b) { qlo = a; qhi = b; }
    if (wr0 >= a && wr0 < b) { wlo = a; whi = b; }
    if (wr1 >= a && wr1 < b) { wlo2 = a; }
    if (q0 >= a && q0 < b) ks = a;
    if (q0 + 63 >= a && q0 + 63 < b) ke = b;
  }
  const bool uniform = (wlo == wlo2);
  const int k_begin = ks & ~63;

  s16x8 qf[5];
  {
    const unsigned short* qp = Qb + ((size_t)h * S_LEN + q0 + w * 32 + cq) * HDIM + hi * 8;
#pragma unroll
    for (int kk = 0; kk < 5; ++kk) qf[kk] = *(const s16x8*)(qp + kk * 16);
  }

  int kA[5], vA[5], kO[5], vO[5];
#pragma unroll
  for (int i = 0; i < 5; ++i) {
    int ch = t + i * 128;
    int kr = ch / 10, kc = ch % 10;
    kA[i] = kr * 128 + ((kc ^ (kr & 15)) << 3);
    kO[i] = ch * 8;
    int vd = ch >> 3, vk = ch & 7;
    vA[i] = vd * 128 + ((vk ^ (vd & 15)) << 3);
    vO[i] = ch * 8;
  }
  const unsigned short* kcur = Kb + (size_t)h * S_LEN * HDIM + (size_t)k_begin * HDIM;
  const unsigned short* vcur = Vt + ((size_t)h * 64 + (k_begin >> 6)) * 5120;

  s16x8 onesf;
#pragma unroll
  for (int i = 0; i < 8; ++i) onesf[i] = (short)(unsigned short)0x3F80;

  const f32x16 z16 = {0.f,0.f,0.f,0.f,0.f,0.f,0.f,0.f,0.f,0.f,0.f,0.f,0.f,0.f,0.f,0.f};
  f32x16 o0 = z16, o1 = z16, o2 = z16;

  s16x8 kreg[5], vreg[5];
#pragma unroll
  for (int i = 0; i < 5; ++i) {
    kreg[i] = *(const s16x8*)(kcur + kO[i]);
    vreg[i] = *(const s16x8*)(vcur + vO[i]);
  }

  for (int k0 = k_begin; k0 < ke; k0 += 64) {
    __syncthreads();
#pragma unroll
    for (int i = 0; i < 5; ++i) {
      *(s16x8*)&Kl[kA[i]] = kreg[i];
      *(s16x8*)&Vl[vA[i]] = vreg[i];
    }
    if (k0 + 64 < ke) {
      kcur += 5120; vcur += 5120;
#pragma unroll
      for (int i = 0; i < 5; ++i) {
        kreg[i] = *(const s16x8*)(kcur + kO[i]);
        vreg[i] = *(const s16x8*)(vcur + vO[i]);
      }
    }
    __syncthreads();

    f32x16 sc0 = z16, sc1 = z16;
    __builtin_amdgcn_s_setprio(1);
#pragma unroll
    for (int kk = 0; kk < 5; ++kk) {
      const int cb = ((2 * kk + hi) ^ (cq & 15)) << 3;
      s16x8 kf0 = *(const s16x8*)&Kl[cq * 128 + cb];
      s16x8 kf1 = *(const s16x8*)&Kl[(32 + cq) * 128 + cb];
      sc0 = mfma32(kf0, qf[kk], sc0);
      sc1 = mfma32(kf1, qf[kk], sc1);
    }
    __builtin_amdgcn_s_setprio(0);

    if (!(uniform && k0 >= wlo && k0 + 64 <= whi)) {
#pragma unroll
      for (int r = 0; r < 16; ++r) {
        int key0 = k0 + (r & 3) + 8 * (r >> 2) + 4 * hi;
        int key1 = key0 + 32;
        sc0[r] = (key0 >= qlo && key0 < qhi) ? sc0[r] : -3e38f;
        sc1[r] = (key1 >= qlo && key1 < qhi) ? sc1[r] : -3e38f;
      }
    }

    float pv0[16], pv1[16];
#pragma unroll
    for (int r = 0; r < 16; ++r) {
      pv0[r] = fexp2(sc0[r]);
      pv1[r] = fexp2(sc1[r]);
    }

    unsigned pk0[4][2], pk1[4][2];
#pragma unroll
    for (int q8 = 0; q8 < 4; ++q8)
#pragma unroll
      for (int i = 0; i < 2; ++i) {
        pk0[q8][i] = cvtpk_bf16(pv0[4 * q8 + 2 * i], pv0[4 * q8 + 2 * i + 1]);
        pk1[q8][i] = cvtpk_bf16(pv1[4 * q8 + 2 * i], pv1[4 * q8 + 2 * i + 1]);
      }

    __builtin_amdgcn_s_setprio(1);
#pragma unroll
    for (int kk = 0; kk < 4; ++kk) {
      const int e = (kk & 1) * 2;
      unsigned a0, a1, b0, b1;
      if (kk < 2) { a0 = pk0[e][0]; b0 = pk0[e + 1][0]; a1 = pk0[e][1]; b1 = pk0[e + 1][1]; }
      else        { a0 = pk1[e][0]; b0 = pk1[e + 1][0]; a1 = pk1[e][1]; b1 = pk1[e + 1][1]; }
      auto s0 = __builtin_amdgcn_permlane32_swap(a0, b0, false, false);
      auto s1 = __builtin_amdgcn_permlane32_swap(a1, b1, false, false);
      union { unsigned u[4]; s16x8 v; } fr_;
      fr_.u[0] = s0[0]; fr_.u[1] = s1[0]; fr_.u[2] = s0[1]; fr_.u[3] = s1[1];
      const int cb = ((2 * kk + hi) ^ (cq & 15)) << 3;
      s16x8 vf0 = *(const s16x8*)&Vl[cq * 128 + cb];
      s16x8 vf1 = *(const s16x8*)&Vl[(32 + cq) * 128 + cb];
      s16x8 vf2 = (cq < 16) ? *(const s16x8*)&Vl[(64 + cq) * 128 + cb] : onesf;
      o0 = mfma32(fr_.v, vf0, o0);
      o1 = mfma32(fr_.v, vf1, o1);
      o2 = mfma32(fr_.v, vf2, o2);
    }
    __builtin_amdgcn_s_setprio(0);
  }

#pragma unroll
  for (int r = 0; r < 16; ++r) {
    float lsum = __shfl(o2[r], 16 | (lane & 32));
    float inv = (lsum > 0.f) ? 1.f / lsum : 0.f;
    const int crow = (r & 3) + 8 * (r >> 2) + 4 * hi;
    int srow = q0 + w * 32 + crow;
    size_t base = (size_t)srow * EMB + h * HDIM;
    ctx[base + cq] = f2bf(o0[r] * inv);
    ctx[base + 32 + cq] = f2bf(o1[r] * inv);
    if (cq < 16) ctx[base + 64 + cq] = f2bf(o2[r] * inv);
  }
}

// ---------------- launch ----------------
extern "C" void kernel_launch(void* const* d_in, const int* in_sizes, int n_in,
                              void* d_out, int out_size, void* d_ws, size_t ws_size,
                              hipStream_t stream) {
  const float* x      = (const float*)d_in[0];
  const int*   cu     = (const int*)d_in[1];
  const float* rope   = (const float*)d_in[2];
  const float* w_qkv  = (const float*)d_in[3];
  const float* b_qkv  = (const float*)d_in[4];
  const float* w_proj = (const float*)d_in[5];
  const float* b_proj = (const float*)d_in[6];
  float* out = (float*)d_out;
  const int ncu = in_sizes[1];

  char* ws = (char*)d_ws;
  unsigned short* xb     = (unsigned short*)(ws + 0);          // 10485760 B
  unsigned short* wqkvb  = (unsigned short*)(ws + 10485760);   // 9830400 B
  unsigned short* wprojb = (unsigned short*)(ws + 20316160);   // 3276800 B
  float*          cosT   = (float*)(ws + 23592960);            // 655360 B
  float*          sinT   = (float*)(ws + 24248320);            // 655360 B
  unsigned short* qkvb   = (unsigned short*)(ws + 24903680);   // 31457280 B
  unsigned short* Qb     = (unsigned short*)(ws + 56360960);   // 10485760 B ([H][S][80])
  unsigned short* Kb     = (unsigned short*)(ws + 68943872);   // 10485760 B
  unsigned short* Vt     = (unsigned short*)(ws + 81526784);   // 10485760 B (tiled)
  unsigned short* ctxb   = (unsigned short*)(ws + 92012544);   // 10485760 B

  fused_pre_kernel<<<12160, 256, 0, stream>>>(x, w_qkv, w_proj, rope,
                                              xb, wqkvb, wprojb, cosT, sinT);

  gemm256_kernel<1><<<240, 512, 0, stream>>>(xb, wqkvb, b_qkv, (void*)qkvb,
                                             4096, 3840, 1280, 15, 16);
  rope_split_kernel<<<dim3(64, 16), 256, 0, stream>>>(qkvb, cosT, sinT, Qb, Kb, Vt);
  attn_kernel<<<1024, 128, 0, stream>>>(Qb, Kb, Vt, cu, ncu, ctxb);
  gemm128_kernel<0><<<320, 256, 0, stream>>>(ctxb, wprojb, b_proj, (void*)out,
                                             4096, 1280, 1280, 10, 32);
}